// Round 8
// baseline (10142.715 us; speedup 1.0000x reference)
//
#include <hip/hip_runtime.h>
#include <math.h>

// Problem dims
constexpr int S_   = 70;
constexpr int B_   = 16;
constexpr int SB_  = 1120;     // S*B
constexpr int NT_  = 32000;    // NTOKEN
constexpr int W1S_ = 32001;    // odeW1 row stride (NTOKEN+1)
constexpr int NBLK = 169;      // persistent LSTM grid (co-resident on 256 CUs)

typedef __attribute__((ext_vector_type(8))) short bf16x8;
typedef __attribute__((ext_vector_type(4))) float f32x4;

__device__ __forceinline__ float sigm(float x){ return 1.f/(1.f+__expf(-x)); }
__device__ __forceinline__ float softplusf(float x){ return x > 15.f ? x : log1pf(__expf(x)); }

__device__ __forceinline__ unsigned short f2bf(float f){
    union{float f; unsigned u;} c; c.f = f;
    unsigned u = c.u;
    unsigned r = (u + 0x7fffu + ((u >> 16) & 1u)) >> 16;
    return (unsigned short)r;
}
__device__ __forceinline__ float bfu(unsigned short us){
    union{unsigned u; float f;} c; c.u = ((unsigned)us) << 16; return c.f;
}

// ---------------------------------------------------------------------------
// grid-wide barrier (all blocks co-resident; device-scope atomics + fences).
__device__ __forceinline__ void gbar(int* cnt, int* gen, int nb)
{
    __threadfence();      // release: every thread drains/flushes its stores
    __syncthreads();
    if (threadIdx.x == 0){
        int g = __hip_atomic_load(gen, __ATOMIC_ACQUIRE, __HIP_MEMORY_SCOPE_AGENT);
        int v = __hip_atomic_fetch_add(cnt, 1, __ATOMIC_ACQ_REL, __HIP_MEMORY_SCOPE_AGENT);
        if (v == nb - 1){
            __hip_atomic_store(cnt, 0, __ATOMIC_RELAXED, __HIP_MEMORY_SCOPE_AGENT);
            __hip_atomic_fetch_add(gen, 1, __ATOMIC_ACQ_REL, __HIP_MEMORY_SCOPE_AGENT);
        } else {
            while (__hip_atomic_load(gen, __ATOMIC_ACQUIRE, __HIP_MEMORY_SCOPE_AGENT) == g)
                __builtin_amdgcn_s_sleep(2);
        }
    }
    __syncthreads();
    __threadfence();      // acquire: invalidate before reading others' writes
}

// ---------------------------------------------------------------------------
// All six LSTM weight conversions in one launch: fp32 [R][K] -> bf16 [R][Kp]
__global__ __launch_bounds__(256) void cvt_pack_all_k(
    const float* __restrict__ s0, unsigned short* __restrict__ d0,
    const float* __restrict__ s1, unsigned short* __restrict__ d1,
    const float* __restrict__ s2, unsigned short* __restrict__ d2,
    const float* __restrict__ s3, unsigned short* __restrict__ d3,
    const float* __restrict__ s4, unsigned short* __restrict__ d4,
    const float* __restrict__ s5, unsigned short* __restrict__ d5)
{
    int seg = blockIdx.y;
    const float* src; unsigned short* dst; int R, K, Kp;
    switch(seg){
      case 0: src=s0; dst=d0; R=4600; K=400;  Kp=416;  break;
      case 1: src=s1; dst=d1; R=4600; K=1150; Kp=1152; break;
      case 2: src=s2; dst=d2; R=4600; K=1150; Kp=1152; break;
      case 3: src=s3; dst=d3; R=4600; K=1150; Kp=1152; break;
      case 4: src=s4; dst=d4; R=1600; K=1150; Kp=1152; break;
      default:src=s5; dst=d5; R=1600; K=400;  Kp=416;  break;
    }
    long long idx = (long long)blockIdx.x*256 + threadIdx.x;
    long long tot = (long long)R*Kp;
    if (idx >= tot) return;
    int r = (int)(idx / Kp), kk = (int)(idx - (long long)r*Kp);
    float v = (kk < K) ? src[(size_t)r*K + kk] : 0.f;
    dst[idx] = f2bf(v);
}

// Abf[1120][800]: k<400 -> x3[m][k], else Hacc[m][k-400]
__global__ __launch_bounds__(256) void cvt_catA_k(const float* __restrict__ x3,
                                                  const float* __restrict__ Hacc,
                                                  unsigned short* __restrict__ Abf)
{
    int idx = blockIdx.x*256 + threadIdx.x;
    if (idx >= SB_*800) return;
    int m = idx / 800, k = idx - m*800;
    float v = (k < 400) ? x3[(size_t)m*400 + k] : Hacc[(size_t)m*400 + (k-400)];
    Abf[idx] = f2bf(v);
}

// Fused: Bbf[32000][800] row-major AND BbfT[800][32000] transposed, single read.
__global__ __launch_bounds__(256) void cvt_catB2_k(const float* __restrict__ decW,
                                                   const float* __restrict__ odeW2,
                                                   unsigned short* __restrict__ Bbf,
                                                   unsigned short* __restrict__ BbfT)
{
    __shared__ unsigned short tile[32][72];
    int v0 = blockIdx.x*64, n0 = blockIdx.y*32;
    int tx = threadIdx.x & 31;
    int vy = threadIdx.x >> 5;
    #pragma unroll
    for (int i = 0; i < 8; ++i){
        int v = v0 + i*8 + vy;
        int n = n0 + tx;
        float val = (n < 400) ? decW[(size_t)v*400 + n] : odeW2[(size_t)v*400 + (n-400)];
        unsigned short us = f2bf(val);
        tile[tx][v - v0] = us;
        Bbf[(size_t)v*800 + n] = us;
    }
    __syncthreads();
    int vx = threadIdx.x & 63;
    int ny = threadIdx.x >> 6;
    #pragma unroll
    for (int i = 0; i < 8; ++i){
        int n = n0 + i*4 + ny;
        BbfT[(size_t)n*NT_ + v0 + vx] = tile[n - n0][vx];
    }
}

// Wxbf[400][32000] = bf16(odeW1[:,1:])
__global__ __launch_bounds__(256) void cvt_wx_k(const float* __restrict__ odeW1,
                                                unsigned short* __restrict__ Wxbf)
{
    long long idx = (long long)blockIdx.x*256 + threadIdx.x;
    if (idx >= (long long)400*NT_) return;
    int m = (int)(idx / NT_), v = (int)(idx - (long long)m*NT_);
    Wxbf[idx] = f2bf(odeW1[(size_t)m*W1S_ + 1 + v]);
}

// ---------------------------------------------------------------------------
// Embedding gather -> bf16 A-layout: x0A[t][b][k] (stride 416, zero-padded)
__global__ __launch_bounds__(256) void embed_bf_k(const int* __restrict__ tok,
                                                  const float* __restrict__ emb,
                                                  unsigned short* __restrict__ x0A)
{
    int t = blockIdx.x;
    __shared__ int tk[16];
    if (threadIdx.x < 16) tk[threadIdx.x] = tok[t*16 + threadIdx.x];
    __syncthreads();
    for (int idx = threadIdx.x; idx < 16*416; idx += 256){
        int b = idx / 416, k = idx - b*416;
        float v = (k < 400) ? emb[(size_t)tk[b]*400 + k] : 0.f;
        x0A[(size_t)t*16*416 + idx] = f2bf(v);
    }
}

// dst[j*16+b] = src[b*dh+j]  (c-state init)
__global__ __launch_bounds__(256) void transpose16_k(const float* __restrict__ src,
                                                     float* __restrict__ dst, int dh)
{
    int idx = blockIdx.x*256 + threadIdx.x;
    if (idx < dh*16){ int j = idx >> 4, b = idx & 15; dst[idx] = src[b*dh + j]; }
}

// h0 [16][Dh] fp32 -> hb [16][SA] bf16
__global__ __launch_bounds__(256) void cvt_h0_k(const float* __restrict__ h0,
                                                unsigned short* __restrict__ hb, int Dh, int SA)
{
    int idx = blockIdx.x*256 + threadIdx.x;
    if (idx >= 16*Dh) return;
    int b = idx / Dh, j = idx - b*Dh;
    hb[(size_t)b*SA + j] = f2bf(h0[idx]);
}

// ---------------------------------------------------------------------------
// K-segment dot with 4 accumulator chains.
__device__ __forceinline__ void dotseg(const unsigned short* __restrict__ a,
                                       const unsigned short* __restrict__ b,
                                       int s, int e, int kq,
                                       f32x4& c0, f32x4& c1, f32x4& c2, f32x4& c3)
{
    int k0 = s;
    for (; k0 + 128 <= e; k0 += 128){
        bf16x8 a0 = *(const bf16x8*)(a + k0 + kq);
        bf16x8 b0 = *(const bf16x8*)(b + k0 + kq);
        bf16x8 a1 = *(const bf16x8*)(a + k0 + 32 + kq);
        bf16x8 b1 = *(const bf16x8*)(b + k0 + 32 + kq);
        bf16x8 a2 = *(const bf16x8*)(a + k0 + 64 + kq);
        bf16x8 b2 = *(const bf16x8*)(b + k0 + 64 + kq);
        bf16x8 a3 = *(const bf16x8*)(a + k0 + 96 + kq);
        bf16x8 b3 = *(const bf16x8*)(b + k0 + 96 + kq);
        c0 = __builtin_amdgcn_mfma_f32_16x16x32_bf16(a0, b0, c0, 0,0,0);
        c1 = __builtin_amdgcn_mfma_f32_16x16x32_bf16(a1, b1, c1, 0,0,0);
        c2 = __builtin_amdgcn_mfma_f32_16x16x32_bf16(a2, b2, c2, 0,0,0);
        c3 = __builtin_amdgcn_mfma_f32_16x16x32_bf16(a3, b3, c3, 0,0,0);
    }
    int rem = e - k0;
    if (rem >= 32){
        bf16x8 a0 = *(const bf16x8*)(a + k0 + kq);
        bf16x8 b0 = *(const bf16x8*)(b + k0 + kq);
        c0 = __builtin_amdgcn_mfma_f32_16x16x32_bf16(a0, b0, c0, 0,0,0);
    }
    if (rem >= 64){
        bf16x8 a1 = *(const bf16x8*)(a + k0 + 32 + kq);
        bf16x8 b1 = *(const bf16x8*)(b + k0 + 32 + kq);
        c1 = __builtin_amdgcn_mfma_f32_16x16x32_bf16(a1, b1, c1, 0,0,0);
    }
    if (rem >= 96){
        bf16x8 a2 = *(const bf16x8*)(a + k0 + 64 + kq);
        bf16x8 b2 = *(const bf16x8*)(b + k0 + 64 + kq);
        c2 = __builtin_amdgcn_mfma_f32_16x16x32_bf16(a2, b2, c2, 0,0,0);
    }
}

// ---------------------------------------------------------------------------
// PERSISTENT 3-layer LSTM: all 72 wavefront steps in one kernel, grid barrier
// between steps. Block = one 16-unit j-tile; 16 waves = 4 gates x 4 K-quarters.
__global__ __launch_bounds__(1024) void lstm_persist_k(
    const unsigned short* __restrict__ x0A,
    unsigned short* __restrict__ ys0A, unsigned short* __restrict__ ys1A,
    float* __restrict__ x3,
    unsigned short* __restrict__ h0b, float* __restrict__ c0,
    unsigned short* __restrict__ h1b, float* __restrict__ c1,
    unsigned short* __restrict__ h2b, float* __restrict__ c2,
    const unsigned short* __restrict__ Wih0p, const unsigned short* __restrict__ Whh0p,
    const float* __restrict__ bih0, const float* __restrict__ bhh0,
    const unsigned short* __restrict__ Wih1p, const unsigned short* __restrict__ Whh1p,
    const float* __restrict__ bih1, const float* __restrict__ bhh1,
    const unsigned short* __restrict__ Wih2p, const unsigned short* __restrict__ Whh2p,
    const float* __restrict__ bih2, const float* __restrict__ bhh2,
    int* __restrict__ bar_cnt, int* __restrict__ bar_gen)
{
    int blk = blockIdx.x;
    int layer, jt;
    if      (blk < 72) { layer = 0; jt = blk; }
    else if (blk < 144){ layer = 1; jt = blk - 72; }
    else               { layer = 2; jt = blk - 144; }
    int j0 = jt*16;

    // layer-constant config
    const unsigned short *AxBase, *AhB, *Wi, *Wh;
    const float *bih, *bhh;
    float *cst;
    unsigned short *yoBase = nullptr;
    float *x3Base = nullptr;
    int Kx, Kh, Dh, SAx, SAh;
    if (layer == 0){
        AxBase = x0A; SAx = 416; Kx = 416;
        AhB = h0b; SAh = 1152; Kh = 1152;
        Wi = Wih0p; Wh = Whh0p; bih = bih0; bhh = bhh0; Dh = 1150;
        cst = c0; yoBase = ys0A;
    } else if (layer == 1){
        AxBase = ys0A; SAx = 1152; Kx = 1152;
        AhB = h1b; SAh = 1152; Kh = 1152;
        Wi = Wih1p; Wh = Whh1p; bih = bih1; bhh = bhh1; Dh = 1150;
        cst = c1; yoBase = ys1A;
    } else {
        AxBase = ys1A; SAx = 1152; Kx = 1152;
        AhB = h2b; SAh = 416; Kh = 416;
        Wi = Wih2p; Wh = Whh2p; bih = bih2; bhh = bhh2; Dh = 400;
        cst = c2; x3Base = x3;
    }

    int lane = threadIdx.x & 63, w = threadIdx.x >> 6;   // w = 0..15
    int gate = w & 3, kq4 = w >> 2;
    int am = lane & 15;
    int kq = (lane >> 4) * 8;
    int jn = lane & 15;
    int jrow = j0 + jn; if (jrow > Dh-1) jrow = Dh-1;

    const unsigned short* wx = Wi + (size_t)(gate*Dh + jrow)*SAx;
    const unsigned short* wh = Wh + (size_t)(gate*Dh + jrow)*SAh;

    int nx = Kx >> 5, nh = Kh >> 5;
    int xq0 = ((nx *  kq4     ) >> 2) << 5;
    int xq1 = ((nx * (kq4 + 1)) >> 2) << 5;
    int hq0 = ((nh *  kq4     ) >> 2) << 5;
    int hq1 = ((nh * (kq4 + 1)) >> 2) << 5;

    __shared__ float g16[16][16][17];

    for (int u = 0; u < S_ + 2; ++u){
        int t = u - layer;
        if (t >= 0 && t < S_){
            const unsigned short* ax = AxBase + (size_t)t*16*SAx + (size_t)am*SAx;
            const unsigned short* ah = AhB + (size_t)(t&1)*16*SAh + (size_t)am*SAh;
            unsigned short* hrec = (unsigned short*)AhB + (size_t)((t+1)&1)*16*SAh;

            f32x4 c0v = {0.f,0.f,0.f,0.f}, c1v = {0.f,0.f,0.f,0.f};
            f32x4 c2v = {0.f,0.f,0.f,0.f}, c3v = {0.f,0.f,0.f,0.f};
            dotseg(ax, wx, xq0, xq1, kq, c0v, c1v, c2v, c3v);
            dotseg(ah, wh, hq0, hq1, kq, c0v, c1v, c2v, c3v);
            f32x4 acc = (c0v + c1v) + (c2v + c3v);

            int bm = (lane >> 4) * 4;
            #pragma unroll
            for (int r = 0; r < 4; ++r) g16[w][bm + r][jn] = acc[r];
            __syncthreads();

            if (threadIdx.x < 256){
                int jl = threadIdx.x >> 4, b = threadIdx.x & 15;
                int j = j0 + jl;
                if (j < Dh){
                    float pi = g16[0][b][jl] + g16[4][b][jl] + g16[8][b][jl]  + g16[12][b][jl] + bih[j]      + bhh[j];
                    float pf = g16[1][b][jl] + g16[5][b][jl] + g16[9][b][jl]  + g16[13][b][jl] + bih[Dh+j]   + bhh[Dh+j];
                    float pg = g16[2][b][jl] + g16[6][b][jl] + g16[10][b][jl] + g16[14][b][jl] + bih[2*Dh+j] + bhh[2*Dh+j];
                    float po = g16[3][b][jl] + g16[7][b][jl] + g16[11][b][jl] + g16[15][b][jl] + bih[3*Dh+j] + bhh[3*Dh+j];
                    float cold = cst[j*16 + b];
                    float cnew = sigm(pf)*cold + sigm(pi)*tanhf(pg);
                    float h    = sigm(po)*tanhf(cnew);
                    cst[j*16 + b] = cnew;
                    unsigned short hb16 = f2bf(h);
                    hrec[(size_t)b*SAh + j] = hb16;
                    if (yoBase) yoBase[(size_t)t*16*1152 + (size_t)b*1152 + j] = hb16;
                    if (x3Base) x3Base[(size_t)t*16*400 + (size_t)b*400 + j] = h;
                }
            }
        }
        if (u < S_ + 1) gbar(bar_cnt, bar_gen, NBLK);
    }
}

// ---------------------------------------------------------------------------
// dvec[j] = Wx[j,:]·decb ; bvec[j] = Wx[j,:]·b2 ; wtd[j] = odeW1[j,0]
__global__ __launch_bounds__(256) void vecs_k(const unsigned short* __restrict__ Wxbf,
                                              const float* __restrict__ odeW1,
                                              const float* __restrict__ decb,
                                              const float* __restrict__ b2v,
                                              float* __restrict__ dvec,
                                              float* __restrict__ bvec,
                                              float* __restrict__ wtd)
{
    int jrow = blockIdx.x;
    __shared__ float r1[256], r2[256];
    const unsigned short* wx = Wxbf + (size_t)jrow*NT_;
    float s1 = 0.f, s2 = 0.f;
    for (int v = threadIdx.x; v < NT_; v += 256){
        float w = bfu(wx[v]); s1 += w*decb[v]; s2 += w*b2v[v];
    }
    r1[threadIdx.x] = s1; r2[threadIdx.x] = s2; __syncthreads();
    for (int s = 128; s > 0; s >>= 1){
        if (threadIdx.x < s){ r1[threadIdx.x] += r1[threadIdx.x+s]; r2[threadIdx.x] += r2[threadIdx.x+s]; }
        __syncthreads();
    }
    if (threadIdx.x == 0){ dvec[jrow] = r1[0]; bvec[jrow] = r2[0]; wtd[jrow] = odeW1[(size_t)jrow*W1S_]; }
}

// ---------------------------------------------------------------------------
// MFMA ODE precompute, LDS stride 44 (conflict mitigation), 16 K-slabs.
__global__ __launch_bounds__(256) void gemm_odeT_k(
    const unsigned short* __restrict__ Wxbf,
    const unsigned short* __restrict__ BbfT,
    float* __restrict__ partials)
{
    __shared__ unsigned short As[128*44];
    __shared__ unsigned short Bs[128*44];
    int n0 = blockIdx.x*128, m0 = blockIdx.y*128, v0 = blockIdx.z*2000;
    int tid = threadIdx.x;
    int lane = tid & 63, wid = tid >> 6;
    int wr = wid >> 1, wc = wid & 1;
    f32x4 acc[4][4] = {};

    int srow = tid >> 1;
    int sk   = (tid & 1) * 16;
    int mL = m0 + srow; if (mL > 399) mL = 399;
    int nL = n0 + srow; if (nL > 799) nL = 799;
    const unsigned short* ap = Wxbf + (size_t)mL*NT_ + v0 + sk;
    const unsigned short* bp = BbfT + (size_t)nL*NT_ + v0 + sk;

    for (int k0 = 0; k0 < 2000; k0 += 32){
        uint4 av0 = *(const uint4*)(ap + k0);
        uint4 av1 = *(const uint4*)(ap + k0 + 8);
        uint4 bv0 = *(const uint4*)(bp + k0);
        uint4 bv1 = *(const uint4*)(bp + k0 + 8);

        __syncthreads();
        *(uint4*)&As[srow*44 + sk]     = av0;
        *(uint4*)&As[srow*44 + sk + 8] = av1;
        *(uint4*)&Bs[srow*44 + sk]     = bv0;
        *(uint4*)&Bs[srow*44 + sk + 8] = bv1;
        __syncthreads();

        int kq = (lane >> 4) * 8;
        int rA = wr*64 + (lane & 15);
        int rB = wc*64 + (lane & 15);
        bf16x8 af[4], bfv[4];
        #pragma unroll
        for (int f = 0; f < 4; ++f){
            af[f]  = *(const bf16x8*)&As[(rA + f*16)*44 + kq];
            bfv[f] = *(const bf16x8*)&Bs[(rB + f*16)*44 + kq];
        }
        #pragma unroll
        for (int fm = 0; fm < 4; ++fm)
            #pragma unroll
            for (int fn = 0; fn < 4; ++fn)
                acc[fm][fn] = __builtin_amdgcn_mfma_f32_16x16x32_bf16(af[fm], bfv[fn], acc[fm][fn], 0, 0, 0);
    }

    float* op = partials + (size_t)blockIdx.z*320000;
    int cm = (lane >> 4) * 4;
    int cn = lane & 15;
    #pragma unroll
    for (int fm = 0; fm < 4; ++fm){
        int mrow0 = m0 + wr*64 + fm*16 + cm;
        #pragma unroll
        for (int fn = 0; fn < 4; ++fn){
            int n = n0 + wc*64 + fn*16 + cn;
            if (n >= 800) continue;
            #pragma unroll
            for (int r = 0; r < 4; ++r){
                int mr = mrow0 + r;
                if (mr < 400) op[mr*800 + n] = acc[fm][fn][r];
            }
        }
    }
}

// sum 16 slabs; scatter to PADDED bf16
__global__ __launch_bounds__(256) void reduce16bf_k(const float* __restrict__ p,
                                                    unsigned short* __restrict__ Qbf,
                                                    unsigned short* __restrict__ Pbf)
{
    int i = blockIdx.x*256 + threadIdx.x;
    if (i >= 320000) return;
    float s = 0.f;
    #pragma unroll
    for (int k = 0; k < 16; ++k) s += p[(size_t)k*320000 + i];
    int m = i / 800, n = i - m*800;
    if (n < 400) Qbf[m*416 + n] = f2bf(s);
    else         Pbf[m*416 + (n-400)] = f2bf(s);
}

// ---------------------------------------------------------------------------
// MFMA small GEMM, LDS stride 44.
__global__ __launch_bounds__(256) void fused_small_mfma_k(
    const float* __restrict__ A, const unsigned short* __restrict__ Bb,
    const float* __restrict__ Gbase, float* __restrict__ OUT,
    const float* __restrict__ vec, float vcoef,
    const float* __restrict__ wt, float tval,
    const float* __restrict__ b1, float dotc, int do_sp)
{
    __shared__ unsigned short As[64*44];
    __shared__ unsigned short Bs[64*44];
    int m0 = blockIdx.y*64, n0 = blockIdx.x*64;
    int tid = threadIdx.x;
    int lane = tid & 63, wid = tid >> 6;
    int wr = wid >> 1, wc = wid & 1;
    f32x4 acc[2][2] = {};

    int rowL = tid >> 2;
    int kL   = (tid & 3) * 8;
    int mG = m0 + rowL;
    int nG = n0 + rowL;

    for (int k0 = 0; k0 < 416; k0 += 32){
        unsigned short a8[8];
        int kb = k0 + kL;
        if (mG < SB_ && kb + 8 <= 400){
            float4 u0 = *(const float4*)(A + (size_t)mG*400 + kb);
            float4 u1 = *(const float4*)(A + (size_t)mG*400 + kb + 4);
            a8[0]=f2bf(u0.x); a8[1]=f2bf(u0.y); a8[2]=f2bf(u0.z); a8[3]=f2bf(u0.w);
            a8[4]=f2bf(u1.x); a8[5]=f2bf(u1.y); a8[6]=f2bf(u1.z); a8[7]=f2bf(u1.w);
        } else {
            #pragma unroll
            for (int i = 0; i < 8; ++i){
                int k = kb + i;
                float v = (mG < SB_ && k < 400) ? A[(size_t)mG*400 + k] : 0.f;
                a8[i] = f2bf(v);
            }
        }
        uint4 bv = {0,0,0,0};
        if (nG < 400) bv = *(const uint4*)(Bb + (size_t)nG*416 + kb);
        __syncthreads();
        #pragma unroll
        for (int i = 0; i < 4; ++i)
            *(unsigned*)&As[rowL*44 + kL + 2*i] = (unsigned)a8[2*i] | ((unsigned)a8[2*i+1] << 16);
        *(uint4*)&Bs[rowL*44 + kL] = bv;
        __syncthreads();

        int kq = (lane >> 4) * 8;
        int rA = wr*32 + (lane & 15);
        int rB = wc*32 + (lane & 15);
        bf16x8 af[2], bfv[2];
        af[0]  = *(const bf16x8*)&As[(rA     )*44 + kq];
        af[1]  = *(const bf16x8*)&As[(rA + 16)*44 + kq];
        bfv[0] = *(const bf16x8*)&Bs[(rB     )*44 + kq];
        bfv[1] = *(const bf16x8*)&Bs[(rB + 16)*44 + kq];
        #pragma unroll
        for (int fm = 0; fm < 2; ++fm)
            #pragma unroll
            for (int fn = 0; fn < 2; ++fn)
                acc[fm][fn] = __builtin_amdgcn_mfma_f32_16x16x32_bf16(af[fm], bfv[fn], acc[fm][fn], 0, 0, 0);
    }

    int cm = (lane >> 4) * 4, cn = lane & 15;
    #pragma unroll
    for (int fm = 0; fm < 2; ++fm){
        #pragma unroll
        for (int fn = 0; fn < 2; ++fn){
            int n = n0 + wc*32 + fn*16 + cn;
            if (n >= 400) continue;
            #pragma unroll
            for (int r = 0; r < 4; ++r){
                int m = m0 + wr*32 + fm*16 + cm + r;
                if (m >= SB_) continue;
                float s = dotc*acc[fm][fn][r];
                if (Gbase) s += Gbase[(size_t)m*400 + n];
                if (vec)   s += vcoef*vec[n];
                if (wt)    s += tval*wt[n];
                if (b1)    s += b1[n];
                OUT[(size_t)m*400 + n] = do_sp ? softplusf(s) : s;
            }
        }
    }
}

// H = softplus(Gy + t*wt + b1)
__global__ __launch_bounds__(256) void stage1_k(const float* __restrict__ Gy, float* __restrict__ H,
                                                const float* __restrict__ wt, float tval,
                                                const float* __restrict__ b1)
{
    int sb = blockIdx.x;
    for (int n = threadIdx.x; n < 400; n += 256){
        float s = Gy[(size_t)sb*400 + n] + tval*wt[n] + b1[n];
        H[(size_t)sb*400 + n] = softplusf(s);
    }
}

// Hs = dt/6*(H1+2H2+2H3+H4); Hacc += Hs
__global__ __launch_bounds__(256) void hs_k(const float* __restrict__ H1, const float* __restrict__ H2,
                                            const float* __restrict__ H3, const float* __restrict__ H4,
                                            float* __restrict__ Hs, float* __restrict__ Hacc, int n)
{
    int i = blockIdx.x*256 + threadIdx.x;
    if (i < n){
        float v = (1.f/12.f)*(H1[i] + 2.f*H2[i] + 2.f*H3[i] + H4[i]);
        Hs[i] = v;
        Hacc[i] += v;
    }
}

// ---------------------------------------------------------------------------
// MFMA decode, 256x128 tiles, LDS stride 44.
__global__ __launch_bounds__(512) void decode_mfma_k(
    const unsigned short* __restrict__ Abf,
    const unsigned short* __restrict__ Bbf,
    const float* __restrict__ decb, const float* __restrict__ b2v,
    float* __restrict__ z)
{
    __shared__ unsigned short As[256*44];
    __shared__ unsigned short Bs[128*44];
    int n0 = blockIdx.x*128, m0 = blockIdx.y*256;
    int tid = threadIdx.x;
    int lane = tid & 63, wid = tid >> 6;
    int wr = wid >> 1, wc = wid & 1;
    f32x4 acc[4][4] = {};

    int srA = tid >> 1, skA = (tid & 1)*16;
    int srB = tid >> 2, skB = (tid & 3)*8;

    for (int k0 = 0; k0 < 800; k0 += 32){
        uint4 av0 = {0,0,0,0}, av1 = {0,0,0,0};
        int m = m0 + srA;
        if (m < SB_){
            const uint4* ap = (const uint4*)(Abf + (size_t)m*800 + k0 + skA);
            av0 = ap[0]; av1 = ap[1];
        }
        uint4 bv = *(const uint4*)(Bbf + (size_t)(n0 + srB)*800 + k0 + skB);

        __syncthreads();
        *(uint4*)&As[srA*44 + skA]     = av0;
        *(uint4*)&As[srA*44 + skA + 8] = av1;
        *(uint4*)&Bs[srB*44 + skB]     = bv;
        __syncthreads();

        int kq = (lane >> 4) * 8;
        int rA = wr*64 + (lane & 15);
        int rB = wc*64 + (lane & 15);
        bf16x8 af[4], bfv[4];
        #pragma unroll
        for (int f = 0; f < 4; ++f){
            af[f]  = *(const bf16x8*)&As[(rA + f*16)*44 + kq];
            bfv[f] = *(const bf16x8*)&Bs[(rB + f*16)*44 + kq];
        }
        #pragma unroll
        for (int fm = 0; fm < 4; ++fm)
            #pragma unroll
            for (int fn = 0; fn < 4; ++fn)
                acc[fm][fn] = __builtin_amdgcn_mfma_f32_16x16x32_bf16(af[fm], bfv[fn], acc[fm][fn], 0, 0, 0);
    }

    int cm = (lane >> 4) * 4;
    int cn = lane & 15;
    #pragma unroll
    for (int fm = 0; fm < 4; ++fm){
        int mrow0 = m0 + wr*64 + fm*16 + cm;
        #pragma unroll
        for (int fn = 0; fn < 4; ++fn){
            int n = n0 + wc*64 + fn*16 + cn;
            float db = decb[n] + b2v[n];
            #pragma unroll
            for (int r = 0; r < 4; ++r){
                int mr = mrow0 + r;
                if (mr < SB_) z[(size_t)mr*NT_ + n] = acc[fm][fn][r] + db;
            }
        }
    }
}

// ---------------------------------------------------------------------------
// Fused log-softmax: row resident in registers.
__global__ __launch_bounds__(1024) void softmax_k(float* __restrict__ z)
{
    int r = blockIdx.x;
    float* zr = z + (size_t)r*NT_;
    int tid = threadIdx.x;
    __shared__ float sm[1024];
    float4 v[8];
    float mx = -1e30f;
    #pragma unroll
    for (int i = 0; i < 8; ++i){
        int base = i*4096 + tid*4;
        if (base < NT_){
            v[i] = *(const float4*)(zr + base);
            mx = fmaxf(mx, fmaxf(fmaxf(v[i].x, v[i].y), fmaxf(v[i].z, v[i].w)));
        } else {
            v[i].x = v[i].y = v[i].z = v[i].w = 0.f;
        }
    }
    sm[tid] = mx; __syncthreads();
    for (int s = 512; s > 0; s >>= 1){
        if (tid < s) sm[tid] = fmaxf(sm[tid], sm[tid+s]);
        __syncthreads();
    }
    mx = sm[0]; __syncthreads();
    float sum = 0.f;
    #pragma unroll
    for (int i = 0; i < 8; ++i){
        int base = i*4096 + tid*4;
        if (base < NT_){
            sum += __expf(v[i].x - mx) + __expf(v[i].y - mx)
                 + __expf(v[i].z - mx) + __expf(v[i].w - mx);
        }
    }
    sm[tid] = sum; __syncthreads();
    for (int s = 512; s > 0; s >>= 1){
        if (tid < s) sm[tid] += sm[tid+s];
        __syncthreads();
    }
    float sinv = 1.f / sm[0];
    #pragma unroll
    for (int i = 0; i < 8; ++i){
        int base = i*4096 + tid*4;
        if (base < NT_){
            float4 o;
            o.x = logf(__expf(v[i].x - mx)*sinv + 1e-8f);
            o.y = logf(__expf(v[i].y - mx)*sinv + 1e-8f);
            o.z = logf(__expf(v[i].z - mx)*sinv + 1e-8f);
            o.w = logf(__expf(v[i].w - mx)*sinv + 1e-8f);
            *(float4*)(zr + base) = o;
        }
    }
}

// ---------------------------------------------------------------------------
extern "C" void kernel_launch(void* const* d_in, const int* in_sizes, int n_in,
                              void* d_out, int out_size, void* d_ws, size_t ws_size,
                              hipStream_t stream)
{
    const int*   tokens = (const int*)  d_in[0];
    const float* h0_0 = (const float*)d_in[1];
    const float* c0_0 = (const float*)d_in[2];
    const float* Wih0 = (const float*)d_in[3];
    const float* Whh0 = (const float*)d_in[4];
    const float* bih0 = (const float*)d_in[5];
    const float* bhh0 = (const float*)d_in[6];
    const float* h0_1 = (const float*)d_in[7];
    const float* c0_1 = (const float*)d_in[8];
    const float* Wih1 = (const float*)d_in[9];
    const float* Whh1 = (const float*)d_in[10];
    const float* bih1 = (const float*)d_in[11];
    const float* bhh1 = (const float*)d_in[12];
    const float* h0_2 = (const float*)d_in[13];
    const float* c0_2 = (const float*)d_in[14];
    const float* Wih2 = (const float*)d_in[15];
    const float* Whh2 = (const float*)d_in[16];
    const float* bih2 = (const float*)d_in[17];
    const float* bhh2 = (const float*)d_in[18];
    const float* emb  = (const float*)d_in[19];
    const float* decW = (const float*)d_in[20];
    const float* decb = (const float*)d_in[21];
    const float* odeW1= (const float*)d_in[22];
    const float* odeb1= (const float*)d_in[23];
    const float* odeW2= (const float*)d_in[24];
    const float* odeb2= (const float*)d_in[25];

    // workspace carve-up (~215 MB), all chunks 16B-aligned
    float* w = (float*)d_ws;
    size_t off = 0;
    auto alloc = [&](size_t n){ float* p = w + off; off += n; return p; };
    auto allocU = [&](size_t nUsh){ return (unsigned short*)alloc(nUsh/2); };
    unsigned short* x0A  = allocU((size_t)S_*16*416);
    unsigned short* ys0A = allocU((size_t)S_*16*1152);
    unsigned short* ys1A = allocU((size_t)S_*16*1152);
    float* x3   = alloc((size_t)SB_*400);
    unsigned short* h0b = allocU((size_t)2*16*1152); float* c0b = alloc(1152*16);
    unsigned short* h1b = allocU((size_t)2*16*1152); float* c1b = alloc(1152*16);
    unsigned short* h2b = allocU((size_t)2*16*416);  float* c2b = alloc(416*16);
    unsigned short* Qbf = allocU((size_t)400*416);
    unsigned short* Pbf = allocU((size_t)400*416);
    float* dvec = alloc(512);
    float* bvec = alloc(512);
    float* wtd  = alloc(512);
    float* Gy   = alloc((size_t)SB_*400);
    float* Hacc = alloc((size_t)SB_*400);
    float* H1   = alloc((size_t)SB_*400);
    float* H2   = alloc((size_t)SB_*400);
    float* H3   = alloc((size_t)SB_*400);
    float* H4   = alloc((size_t)SB_*400);
    float* Hs   = alloc((size_t)SB_*400);
    int*   bar  = (int*)alloc(64);     // [0]=cnt, [16]=gen (separate lines)
    float* partials = alloc((size_t)16*320000);
    unsigned short* Wih0p = allocU((size_t)4600*416);
    unsigned short* Whh0p = allocU((size_t)4600*1152);
    unsigned short* Wih1p = allocU((size_t)4600*1152);
    unsigned short* Whh1p = allocU((size_t)4600*1152);
    unsigned short* Wih2p = allocU((size_t)1600*1152);
    unsigned short* Whh2p = allocU((size_t)1600*416);
    unsigned short* Abf   = allocU((size_t)SB_*800);
    unsigned short* Bbf   = allocU((size_t)NT_*800);
    unsigned short* BbfT  = allocU((size_t)800*NT_);
    unsigned short* Wxbf  = allocU((size_t)400*NT_);
    (void)ws_size; (void)in_sizes; (void)n_in; (void)out_size;

    float* zout = (float*)d_out;

    hipMemsetAsync(Hacc, 0, (size_t)SB_*400*sizeof(float), stream);
    hipMemsetAsync(bar,  0, 64*sizeof(float), stream);
    // zero pad-sensitive buffers (MFMA reads pads; must not be NaN)
    hipMemsetAsync(ys0A, 0, (size_t)S_*16*1152*2, stream);
    hipMemsetAsync(ys1A, 0, (size_t)S_*16*1152*2, stream);
    hipMemsetAsync(h0b,  0, (size_t)2*16*1152*2, stream);
    hipMemsetAsync(h1b,  0, (size_t)2*16*1152*2, stream);
    hipMemsetAsync(h2b,  0, (size_t)2*16*416*2, stream);
    hipMemsetAsync(Qbf,  0, (size_t)400*416*2, stream);
    hipMemsetAsync(Pbf,  0, (size_t)400*416*2, stream);

    // weight conversions (bf16, K zero-padded): all six in one launch
    auto cvtgrid = [](long long n){ return (unsigned)((n + 255) / 256); };
    cvt_pack_all_k<<<dim3(cvtgrid((long long)4600*1152), 6), 256, 0, stream>>>(
        Wih0, Wih0p, Whh0, Whh0p, Wih1, Wih1p, Whh1, Whh1p, Wih2, Wih2p, Whh2, Whh2p);
    cvt_catB2_k<<<dim3(500, 25), 256, 0, stream>>>(decW, odeW2, Bbf, BbfT);
    cvt_wx_k<<<cvtgrid((long long)400*NT_), 256, 0, stream>>>(odeW1, Wxbf);

    // activations + state init
    embed_bf_k<<<S_, 256, 0, stream>>>(tokens, emb, x0A);
    cvt_h0_k<<<(16*1150+255)/256, 256, 0, stream>>>(h0_0, h0b, 1150, 1152);
    cvt_h0_k<<<(16*1150+255)/256, 256, 0, stream>>>(h0_1, h1b, 1150, 1152);
    cvt_h0_k<<<(16*400+255)/256,  256, 0, stream>>>(h0_2, h2b, 400, 416);
    transpose16_k<<<(1150*16+255)/256, 256, 0, stream>>>(c0_0, c0b, 1150);
    transpose16_k<<<(1150*16+255)/256, 256, 0, stream>>>(c0_1, c1b, 1150);
    transpose16_k<<<(400*16+255)/256,  256, 0, stream>>>(c0_2, c2b, 400);

    // persistent 3-layer LSTM (all 72 wavefront steps, internal grid barrier)
    lstm_persist_k<<<NBLK, 1024, 0, stream>>>(x0A, ys0A, ys1A, x3,
        h0b, c0b, h1b, c1b, h2b, c2b,
        Wih0p, Whh0p, bih0, bhh0, Wih1p, Whh1p, bih1, bhh1, Wih2p, Whh2p, bih2, bhh2,
        bar, bar + 16);

    // ODE factorization precompute: [Q|P] = Wx @ BbfT^T via MFMA, 16 K-slabs
    vecs_k<<<400, 256, 0, stream>>>(Wxbf, odeW1, decb, odeb2, dvec, bvec, wtd);
    gemm_odeT_k<<<dim3(7,4,16), 256, 0, stream>>>(Wxbf, BbfT, partials);
    reduce16bf_k<<<(320000+255)/256, 256, 0, stream>>>(partials, Qbf, Pbf);

    // G0 = x3 @ Q^T + dvec
    fused_small_mfma_k<<<dim3(7,18), 256, 0, stream>>>(x3, Qbf, nullptr, Gy,
        dvec, 1.f, nullptr, 0.f, nullptr, 1.f, 0);

    // RK4 in G-space, 2 steps, dt = 0.5
    const float dt = 0.5f;
    for (int n = 0; n < 2; ++n){
        float t0 = n * dt;
        stage1_k<<<SB_, 256, 0, stream>>>(Gy, H1, wtd, t0, odeb1);
        fused_small_mfma_k<<<dim3(7,18), 256, 0, stream>>>(H1, Pbf, Gy, H2,
            bvec, 0.25f, wtd, t0 + 0.25f, odeb1, 0.25f, 1);
        fused_small_mfma_k<<<dim3(7,18), 256, 0, stream>>>(H2, Pbf, Gy, H3,
            bvec, 0.25f, wtd, t0 + 0.25f, odeb1, 0.25f, 1);
        fused_small_mfma_k<<<dim3(7,18), 256, 0, stream>>>(H3, Pbf, Gy, H4,
            bvec, 0.5f, wtd, t0 + 0.5f, odeb1, 0.5f, 1);
        hs_k<<<((SB_*400)+255)/256, 256, 0, stream>>>(H1, H2, H3, H4, Hs, Hacc, SB_*400);
        if (n == 0)
            fused_small_mfma_k<<<dim3(7,18), 256, 0, stream>>>(Hs, Pbf, Gy, Gy,
                bvec, dt, nullptr, 0.f, nullptr, 1.f, 0);
    }

    // A-concat (x3|Hacc) -> bf16, MFMA decode, fused log-softmax
    cvt_catA_k<<<cvtgrid((long long)SB_*800), 256, 0, stream>>>(x3, Hacc, Abf);
    decode_mfma_k<<<dim3(250,5), 512, 0, stream>>>(Abf, Bbf, decb, odeb2, zout);
    softmax_k<<<SB_, 1024, 0, stream>>>(zout);
}

// Round 9
// 2057.600 us; speedup vs baseline: 4.9294x; 4.9294x over previous
//
#include <hip/hip_runtime.h>
#include <math.h>

// Problem dims
constexpr int S_   = 70;
constexpr int B_   = 16;
constexpr int SB_  = 1120;     // S*B
constexpr int NT_  = 32000;    // NTOKEN
constexpr int W1S_ = 32001;    // odeW1 row stride (NTOKEN+1)
constexpr int AST  = 424;      // ode kernel LDS A stride (ushorts)

typedef __attribute__((ext_vector_type(8))) short bf16x8;
typedef __attribute__((ext_vector_type(4))) float f32x4;

__device__ __forceinline__ float sigm(float x){ return 1.f/(1.f+__expf(-x)); }
__device__ __forceinline__ float softplusf(float x){ return x > 15.f ? x : log1pf(__expf(x)); }

__device__ __forceinline__ unsigned short f2bf(float f){
    union{float f; unsigned u;} c; c.f = f;
    unsigned u = c.u;
    unsigned r = (u + 0x7fffu + ((u >> 16) & 1u)) >> 16;
    return (unsigned short)r;
}
__device__ __forceinline__ float bfu(unsigned short us){
    union{unsigned u; float f;} c; c.u = ((unsigned)us) << 16; return c.f;
}

// ---------------------------------------------------------------------------
// All six LSTM weight conversions in one launch: fp32 [R][K] -> bf16 [R][Kp]
__global__ __launch_bounds__(256) void cvt_pack_all_k(
    const float* __restrict__ s0, unsigned short* __restrict__ d0,
    const float* __restrict__ s1, unsigned short* __restrict__ d1,
    const float* __restrict__ s2, unsigned short* __restrict__ d2,
    const float* __restrict__ s3, unsigned short* __restrict__ d3,
    const float* __restrict__ s4, unsigned short* __restrict__ d4,
    const float* __restrict__ s5, unsigned short* __restrict__ d5)
{
    int seg = blockIdx.y;
    const float* src; unsigned short* dst; int R, K, Kp;
    switch(seg){
      case 0: src=s0; dst=d0; R=4600; K=400;  Kp=416;  break;
      case 1: src=s1; dst=d1; R=4600; K=1150; Kp=1152; break;
      case 2: src=s2; dst=d2; R=4600; K=1150; Kp=1152; break;
      case 3: src=s3; dst=d3; R=4600; K=1150; Kp=1152; break;
      case 4: src=s4; dst=d4; R=1600; K=1150; Kp=1152; break;
      default:src=s5; dst=d5; R=1600; K=400;  Kp=416;  break;
    }
    long long idx = (long long)blockIdx.x*256 + threadIdx.x;
    long long tot = (long long)R*Kp;
    if (idx >= tot) return;
    int r = (int)(idx / Kp), kk = (int)(idx - (long long)r*Kp);
    float v = (kk < K) ? src[(size_t)r*K + kk] : 0.f;
    dst[idx] = f2bf(v);
}

// Fused: Bbf[32000][800] row-major AND BbfT[800][32000] transposed, single read.
__global__ __launch_bounds__(256) void cvt_catB2_k(const float* __restrict__ decW,
                                                   const float* __restrict__ odeW2,
                                                   unsigned short* __restrict__ Bbf,
                                                   unsigned short* __restrict__ BbfT)
{
    __shared__ unsigned short tile[32][72];
    int v0 = blockIdx.x*64, n0 = blockIdx.y*32;
    int tx = threadIdx.x & 31;
    int vy = threadIdx.x >> 5;
    #pragma unroll
    for (int i = 0; i < 8; ++i){
        int v = v0 + i*8 + vy;
        int n = n0 + tx;
        float val = (n < 400) ? decW[(size_t)v*400 + n] : odeW2[(size_t)v*400 + (n-400)];
        unsigned short us = f2bf(val);
        tile[tx][v - v0] = us;
        Bbf[(size_t)v*800 + n] = us;
    }
    __syncthreads();
    int vx = threadIdx.x & 63;
    int ny = threadIdx.x >> 6;
    #pragma unroll
    for (int i = 0; i < 8; ++i){
        int n = n0 + i*4 + ny;
        BbfT[(size_t)n*NT_ + v0 + vx] = tile[n - n0][vx];
    }
}

// Wxbf[400][32000] = bf16(odeW1[:,1:])
__global__ __launch_bounds__(256) void cvt_wx_k(const float* __restrict__ odeW1,
                                                unsigned short* __restrict__ Wxbf)
{
    long long idx = (long long)blockIdx.x*256 + threadIdx.x;
    if (idx >= (long long)400*NT_) return;
    int m = (int)(idx / NT_), v = (int)(idx - (long long)m*NT_);
    Wxbf[idx] = f2bf(odeW1[(size_t)m*W1S_ + 1 + v]);
}

// ---------------------------------------------------------------------------
// Embedding gather -> bf16 A-layout: x0A[t][b][k] (stride 416, zero-padded)
__global__ __launch_bounds__(256) void embed_bf_k(const int* __restrict__ tok,
                                                  const float* __restrict__ emb,
                                                  unsigned short* __restrict__ x0A)
{
    int t = blockIdx.x;
    __shared__ int tk[16];
    if (threadIdx.x < 16) tk[threadIdx.x] = tok[t*16 + threadIdx.x];
    __syncthreads();
    for (int idx = threadIdx.x; idx < 16*416; idx += 256){
        int b = idx / 416, k = idx - b*416;
        float v = (k < 400) ? emb[(size_t)tk[b]*400 + k] : 0.f;
        x0A[(size_t)t*16*416 + idx] = f2bf(v);
    }
}

// dst[j*16+b] = src[b*dh+j]  (c-state init)
__global__ __launch_bounds__(256) void transpose16_k(const float* __restrict__ src,
                                                     float* __restrict__ dst, int dh)
{
    int idx = blockIdx.x*256 + threadIdx.x;
    if (idx < dh*16){ int j = idx >> 4, b = idx & 15; dst[idx] = src[b*dh + j]; }
}

// h0 [16][Dh] fp32 -> hb [16][SA] bf16
__global__ __launch_bounds__(256) void cvt_h0_k(const float* __restrict__ h0,
                                                unsigned short* __restrict__ hb, int Dh, int SA)
{
    int idx = blockIdx.x*256 + threadIdx.x;
    if (idx >= 16*Dh) return;
    int b = idx / Dh, j = idx - b*Dh;
    hb[(size_t)b*SA + j] = f2bf(h0[idx]);
}

// ---------------------------------------------------------------------------
// K-segment dot with 4 accumulator chains.
__device__ __forceinline__ void dotseg(const unsigned short* __restrict__ a,
                                       const unsigned short* __restrict__ b,
                                       int s, int e, int kq,
                                       f32x4& c0, f32x4& c1, f32x4& c2, f32x4& c3)
{
    int k0 = s;
    for (; k0 + 128 <= e; k0 += 128){
        bf16x8 a0 = *(const bf16x8*)(a + k0 + kq);
        bf16x8 b0 = *(const bf16x8*)(b + k0 + kq);
        bf16x8 a1 = *(const bf16x8*)(a + k0 + 32 + kq);
        bf16x8 b1 = *(const bf16x8*)(b + k0 + 32 + kq);
        bf16x8 a2 = *(const bf16x8*)(a + k0 + 64 + kq);
        bf16x8 b2 = *(const bf16x8*)(b + k0 + 64 + kq);
        bf16x8 a3 = *(const bf16x8*)(a + k0 + 96 + kq);
        bf16x8 b3 = *(const bf16x8*)(b + k0 + 96 + kq);
        c0 = __builtin_amdgcn_mfma_f32_16x16x32_bf16(a0, b0, c0, 0,0,0);
        c1 = __builtin_amdgcn_mfma_f32_16x16x32_bf16(a1, b1, c1, 0,0,0);
        c2 = __builtin_amdgcn_mfma_f32_16x16x32_bf16(a2, b2, c2, 0,0,0);
        c3 = __builtin_amdgcn_mfma_f32_16x16x32_bf16(a3, b3, c3, 0,0,0);
    }
    int rem = e - k0;
    if (rem >= 32){
        bf16x8 a0 = *(const bf16x8*)(a + k0 + kq);
        bf16x8 b0 = *(const bf16x8*)(b + k0 + kq);
        c0 = __builtin_amdgcn_mfma_f32_16x16x32_bf16(a0, b0, c0, 0,0,0);
    }
    if (rem >= 64){
        bf16x8 a1 = *(const bf16x8*)(a + k0 + 32 + kq);
        bf16x8 b1 = *(const bf16x8*)(b + k0 + 32 + kq);
        c1 = __builtin_amdgcn_mfma_f32_16x16x32_bf16(a1, b1, c1, 0,0,0);
    }
    if (rem >= 96){
        bf16x8 a2 = *(const bf16x8*)(a + k0 + 64 + kq);
        bf16x8 b2 = *(const bf16x8*)(b + k0 + 64 + kq);
        c2 = __builtin_amdgcn_mfma_f32_16x16x32_bf16(a2, b2, c2, 0,0,0);
    }
}

// One wavefront step of the 3-layer LSTM pipeline, MFMA, 4-way K-split.
// Block = one 16-unit j-tile; 16 waves = 4 gates x 4 K-quarters (1024 threads).
__global__ __launch_bounds__(1024) void lstm_mfma_k(int u,
    const unsigned short* __restrict__ x0A,
    unsigned short* __restrict__ ys0A, unsigned short* __restrict__ ys1A,
    float* __restrict__ x3,
    unsigned short* __restrict__ h0b, float* __restrict__ c0,
    unsigned short* __restrict__ h1b, float* __restrict__ c1,
    unsigned short* __restrict__ h2b, float* __restrict__ c2,
    const unsigned short* __restrict__ Wih0p, const unsigned short* __restrict__ Whh0p,
    const float* __restrict__ bih0, const float* __restrict__ bhh0,
    const unsigned short* __restrict__ Wih1p, const unsigned short* __restrict__ Whh1p,
    const float* __restrict__ bih1, const float* __restrict__ bhh1,
    const unsigned short* __restrict__ Wih2p, const unsigned short* __restrict__ Whh2p,
    const float* __restrict__ bih2, const float* __restrict__ bhh2)
{
    int blk = blockIdx.x;
    int layer, jt;
    if      (blk < 72) { layer = 0; jt = blk; }
    else if (blk < 144){ layer = 1; jt = blk - 72; }
    else               { layer = 2; jt = blk - 144; }
    int t = u - layer;
    if (t < 0 || t >= S_) return;
    int j0 = jt*16;

    const unsigned short *Ax, *Ah, *Wi, *Wh;
    const float *bih, *bhh;
    float *cst, *x3o = nullptr;
    unsigned short *yo = nullptr, *hrec;
    int Kx, Kh, Dh, SAx, SAh;
    if (layer == 0){
        Ax = x0A + (size_t)t*16*416; SAx = 416; Kx = 416;
        Ah = h0b + (size_t)(t&1)*16*1152; SAh = 1152; Kh = 1152;
        Wi = Wih0p; Wh = Whh0p; bih = bih0; bhh = bhh0; Dh = 1150;
        cst = c0; hrec = h0b + (size_t)((t+1)&1)*16*1152;
        yo = ys0A + (size_t)t*16*1152;
    } else if (layer == 1){
        Ax = ys0A + (size_t)t*16*1152; SAx = 1152; Kx = 1152;
        Ah = h1b + (size_t)(t&1)*16*1152; SAh = 1152; Kh = 1152;
        Wi = Wih1p; Wh = Whh1p; bih = bih1; bhh = bhh1; Dh = 1150;
        cst = c1; hrec = h1b + (size_t)((t+1)&1)*16*1152;
        yo = ys1A + (size_t)t*16*1152;
    } else {
        Ax = ys1A + (size_t)t*16*1152; SAx = 1152; Kx = 1152;
        Ah = h2b + (size_t)(t&1)*16*416; SAh = 416; Kh = 416;
        Wi = Wih2p; Wh = Whh2p; bih = bih2; bhh = bhh2; Dh = 400;
        cst = c2; hrec = h2b + (size_t)((t+1)&1)*16*416;
        x3o = x3 + (size_t)t*16*400;
    }

    int lane = threadIdx.x & 63, w = threadIdx.x >> 6;   // w = 0..15
    int gate = w & 3, kq4 = w >> 2;
    int am = lane & 15;
    int kq = (lane >> 4) * 8;
    int jn = lane & 15;
    int jrow = j0 + jn; if (jrow > Dh-1) jrow = Dh-1;

    const unsigned short* ax = Ax + (size_t)am*SAx;
    const unsigned short* ah = Ah + (size_t)am*SAh;
    const unsigned short* wx = Wi + (size_t)(gate*Dh + jrow)*SAx;
    const unsigned short* wh = Wh + (size_t)(gate*Dh + jrow)*SAh;

    int nx = Kx >> 5, nh = Kh >> 5;
    int xq0 = ((nx *  kq4     ) >> 2) << 5;
    int xq1 = ((nx * (kq4 + 1)) >> 2) << 5;
    int hq0 = ((nh *  kq4     ) >> 2) << 5;
    int hq1 = ((nh * (kq4 + 1)) >> 2) << 5;

    f32x4 c0v = {0.f,0.f,0.f,0.f}, c1v = {0.f,0.f,0.f,0.f};
    f32x4 c2v = {0.f,0.f,0.f,0.f}, c3v = {0.f,0.f,0.f,0.f};
    dotseg(ax, wx, xq0, xq1, kq, c0v, c1v, c2v, c3v);
    dotseg(ah, wh, hq0, hq1, kq, c0v, c1v, c2v, c3v);
    f32x4 acc = (c0v + c1v) + (c2v + c3v);

    __shared__ float g16[16][16][17];
    int bm = (lane >> 4) * 4;
    #pragma unroll
    for (int r = 0; r < 4; ++r) g16[w][bm + r][jn] = acc[r];
    __syncthreads();

    if (threadIdx.x < 256){
        int jl = threadIdx.x >> 4, b = threadIdx.x & 15;
        int j = j0 + jl;
        if (j < Dh){
            float pi = g16[0][b][jl] + g16[4][b][jl] + g16[8][b][jl]  + g16[12][b][jl] + bih[j]      + bhh[j];
            float pf = g16[1][b][jl] + g16[5][b][jl] + g16[9][b][jl]  + g16[13][b][jl] + bih[Dh+j]   + bhh[Dh+j];
            float pg = g16[2][b][jl] + g16[6][b][jl] + g16[10][b][jl] + g16[14][b][jl] + bih[2*Dh+j] + bhh[2*Dh+j];
            float po = g16[3][b][jl] + g16[7][b][jl] + g16[11][b][jl] + g16[15][b][jl] + bih[3*Dh+j] + bhh[3*Dh+j];
            float cold = cst[j*16 + b];
            float cnew = sigm(pf)*cold + sigm(pi)*tanhf(pg);
            float h    = sigm(po)*tanhf(cnew);
            cst[j*16 + b] = cnew;
            unsigned short hb16 = f2bf(h);
            hrec[(size_t)b*SAh + j] = hb16;
            if (yo)  yo[(size_t)b*1152 + j] = hb16;
            if (x3o) x3o[(size_t)b*400 + j] = h;
        }
    }
}

// ---------------------------------------------------------------------------
// dvec[j] = Wx[j,:]·decb ; bvec[j] = Wx[j,:]·b2 ; wtd[j] = odeW1[j,0]
__global__ __launch_bounds__(256) void vecs_k(const unsigned short* __restrict__ Wxbf,
                                              const float* __restrict__ odeW1,
                                              const float* __restrict__ decb,
                                              const float* __restrict__ b2v,
                                              float* __restrict__ dvec,
                                              float* __restrict__ bvec,
                                              float* __restrict__ wtd)
{
    int jrow = blockIdx.x;
    __shared__ float r1[256], r2[256];
    const unsigned short* wx = Wxbf + (size_t)jrow*NT_;
    float s1 = 0.f, s2 = 0.f;
    for (int v = threadIdx.x; v < NT_; v += 256){
        float w = bfu(wx[v]); s1 += w*decb[v]; s2 += w*b2v[v];
    }
    r1[threadIdx.x] = s1; r2[threadIdx.x] = s2; __syncthreads();
    for (int s = 128; s > 0; s >>= 1){
        if (threadIdx.x < s){ r1[threadIdx.x] += r1[threadIdx.x+s]; r2[threadIdx.x] += r2[threadIdx.x+s]; }
        __syncthreads();
    }
    if (threadIdx.x == 0){ dvec[jrow] = r1[0]; bvec[jrow] = r2[0]; wtd[jrow] = odeW1[(size_t)jrow*W1S_]; }
}

// ---------------------------------------------------------------------------
// MFMA ODE precompute, LDS stride 44, 16 K-slabs.
__global__ __launch_bounds__(256) void gemm_odeT_k(
    const unsigned short* __restrict__ Wxbf,
    const unsigned short* __restrict__ BbfT,
    float* __restrict__ partials)
{
    __shared__ unsigned short As[128*44];
    __shared__ unsigned short Bs[128*44];
    int n0 = blockIdx.x*128, m0 = blockIdx.y*128, v0 = blockIdx.z*2000;
    int tid = threadIdx.x;
    int lane = tid & 63, wid = tid >> 6;
    int wr = wid >> 1, wc = wid & 1;
    f32x4 acc[4][4] = {};

    int srow = tid >> 1;
    int sk   = (tid & 1) * 16;
    int mL = m0 + srow; if (mL > 399) mL = 399;
    int nL = n0 + srow; if (nL > 799) nL = 799;
    const unsigned short* ap = Wxbf + (size_t)mL*NT_ + v0 + sk;
    const unsigned short* bp = BbfT + (size_t)nL*NT_ + v0 + sk;

    for (int k0 = 0; k0 < 2000; k0 += 32){
        uint4 av0 = *(const uint4*)(ap + k0);
        uint4 av1 = *(const uint4*)(ap + k0 + 8);
        uint4 bv0 = *(const uint4*)(bp + k0);
        uint4 bv1 = *(const uint4*)(bp + k0 + 8);

        __syncthreads();
        *(uint4*)&As[srow*44 + sk]     = av0;
        *(uint4*)&As[srow*44 + sk + 8] = av1;
        *(uint4*)&Bs[srow*44 + sk]     = bv0;
        *(uint4*)&Bs[srow*44 + sk + 8] = bv1;
        __syncthreads();

        int kq = (lane >> 4) * 8;
        int rA = wr*64 + (lane & 15);
        int rB = wc*64 + (lane & 15);
        bf16x8 af[4], bfv[4];
        #pragma unroll
        for (int f = 0; f < 4; ++f){
            af[f]  = *(const bf16x8*)&As[(rA + f*16)*44 + kq];
            bfv[f] = *(const bf16x8*)&Bs[(rB + f*16)*44 + kq];
        }
        #pragma unroll
        for (int fm = 0; fm < 4; ++fm)
            #pragma unroll
            for (int fn = 0; fn < 4; ++fn)
                acc[fm][fn] = __builtin_amdgcn_mfma_f32_16x16x32_bf16(af[fm], bfv[fn], acc[fm][fn], 0, 0, 0);
    }

    float* op = partials + (size_t)blockIdx.z*320000;
    int cm = (lane >> 4) * 4;
    int cn = lane & 15;
    #pragma unroll
    for (int fm = 0; fm < 4; ++fm){
        int mrow0 = m0 + wr*64 + fm*16 + cm;
        #pragma unroll
        for (int fn = 0; fn < 4; ++fn){
            int n = n0 + wc*64 + fn*16 + cn;
            if (n >= 800) continue;
            #pragma unroll
            for (int r = 0; r < 4; ++r){
                int mr = mrow0 + r;
                if (mr < 400) op[mr*800 + n] = acc[fm][fn][r];
            }
        }
    }
}

// sum 16 slabs; scatter to PADDED bf16 [416][416] (rows/cols >=400 stay zero)
__global__ __launch_bounds__(256) void reduce16bf_k(const float* __restrict__ p,
                                                    unsigned short* __restrict__ Qbf,
                                                    unsigned short* __restrict__ Pbf)
{
    int i = blockIdx.x*256 + threadIdx.x;
    if (i >= 320000) return;
    float s = 0.f;
    #pragma unroll
    for (int k = 0; k < 16; ++k) s += p[(size_t)k*320000 + i];
    int m = i / 800, n = i - m*800;
    if (n < 400) Qbf[m*416 + n] = f2bf(s);
    else         Pbf[m*416 + (n-400)] = f2bf(s);
}

// ---------------------------------------------------------------------------
// FUSED ODE: G0 GEMM + 2 RK4 steps (4 stages each) + Gy update + Abf output.
// Row-independent in G-space: block owns 32 rows; A (current H) in LDS bf16;
// Gy/comb/Hacc in MFMA-fragment registers; B (Qbf/Pbf [416][416]) from global (L2).
// 8 waves = 2 m-tiles x 4 n-groups; n-tiles nt = ng + 4*i (nt < 25).
__global__ __launch_bounds__(512) void ode_rk4_k(
    const float* __restrict__ x3,
    const unsigned short* __restrict__ Qbf,
    const unsigned short* __restrict__ Pbf,
    const float* __restrict__ dvec, const float* __restrict__ bvec,
    const float* __restrict__ wtd, const float* __restrict__ b1,
    unsigned short* __restrict__ Abf)
{
    __shared__ unsigned short Al[32*AST];
    int m0 = blockIdx.x*32;
    int tid = threadIdx.x;
    int lane = tid & 63, w = tid >> 6;
    int mt = w & 1, ng = (w >> 1) & 3;
    int cm = (lane >> 4)*4;
    int cn = lane & 15;
    int kq = (lane >> 4)*8;

    // initial A = bf16(x3 rows); also global Abf low half
    #pragma unroll
    for (int i = 0; i < 25; ++i){
        int idx = i*512 + tid;            // 32*400 = 12800 = 25*512
        int m = idx / 400, k = idx - m*400;
        unsigned short us = f2bf(x3[(size_t)(m0+m)*400 + k]);
        Al[m*AST + k] = us;
        Abf[(size_t)(m0+m)*800 + k] = us;
    }
    { int m = tid >> 4, k = 400 + (tid & 15); Al[m*AST + k] = 0; }  // zero K-pad
    __syncthreads();

    float gy[7][4], hacc[7][4], comb[7][4];
    float vd[7], vb[7], vw[7], v1[7];
    #pragma unroll
    for (int i = 0; i < 7; ++i){
        int nt = ng + 4*i;
        if (nt < 25){
            int n = nt*16 + cn;
            vd[i] = dvec[n]; vb[i] = bvec[n]; vw[i] = wtd[n]; v1[i] = b1[n];
        } else { vd[i]=0.f; vb[i]=0.f; vw[i]=0.f; v1[i]=0.f; }
        #pragma unroll
        for (int r = 0; r < 4; ++r) hacc[i][r] = 0.f;
    }

    const unsigned short* arow = &Al[(size_t)(mt*16 + cn)*AST + kq];
    f32x4 t7[7];
    auto gemmB = [&](const unsigned short* Bb){
        #pragma unroll
        for (int i = 0; i < 7; ++i){
            f32x4 a = {0.f,0.f,0.f,0.f};
            int nt = ng + 4*i;
            if (nt < 25){
                const unsigned short* brow = Bb + (size_t)(nt*16 + cn)*416 + kq;
                #pragma unroll
                for (int k0 = 0; k0 < 416; k0 += 32){
                    bf16x8 av = *(const bf16x8*)(arow + k0);
                    bf16x8 bv = *(const bf16x8*)(brow + k0);
                    a = __builtin_amdgcn_mfma_f32_16x16x32_bf16(av, bv, a, 0,0,0);
                }
            }
            t7[i] = a;
        }
    };
    // write fragment values (as bf16) into Al as next A operand
    auto writeA = [&](float vals[7][4]){
        __syncthreads();   // all waves done reading Al
        #pragma unroll
        for (int i = 0; i < 7; ++i){
            int nt = ng + 4*i;
            if (nt < 25){
                int n = nt*16 + cn;
                #pragma unroll
                for (int r = 0; r < 4; ++r)
                    Al[(mt*16 + cm + r)*AST + n] = f2bf(vals[i][r]);
            }
        }
        __syncthreads();
    };

    // G0 = x3 @ Q^T + dvec
    gemmB(Qbf);
    #pragma unroll
    for (int i = 0; i < 7; ++i)
        #pragma unroll
        for (int r = 0; r < 4; ++r) gy[i][r] = t7[i][r] + vd[i];

    const float dt = 0.5f;
    for (int st = 0; st < 2; ++st){
        float t0 = st * dt;
        float hs[7][4];
        // H1 = softplus(Gy + t0*wt + b1)
        #pragma unroll
        for (int i = 0; i < 7; ++i)
            #pragma unroll
            for (int r = 0; r < 4; ++r){
                float v = softplusf(gy[i][r] + t0*vw[i] + v1[i]);
                hs[i][r] = v; comb[i][r] = v;
            }
        writeA(hs);
        // H2: coef 0.25, weight 2
        gemmB(Pbf);
        #pragma unroll
        for (int i = 0; i < 7; ++i)
            #pragma unroll
            for (int r = 0; r < 4; ++r){
                float v = softplusf(0.25f*t7[i][r] + gy[i][r] + 0.25f*vb[i] + (t0+0.25f)*vw[i] + v1[i]);
                hs[i][r] = v; comb[i][r] += 2.f*v;
            }
        writeA(hs);
        // H3: coef 0.25, weight 2
        gemmB(Pbf);
        #pragma unroll
        for (int i = 0; i < 7; ++i)
            #pragma unroll
            for (int r = 0; r < 4; ++r){
                float v = softplusf(0.25f*t7[i][r] + gy[i][r] + 0.25f*vb[i] + (t0+0.25f)*vw[i] + v1[i]);
                hs[i][r] = v; comb[i][r] += 2.f*v;
            }
        writeA(hs);
        // H4: coef 0.5, weight 1
        gemmB(Pbf);
        #pragma unroll
        for (int i = 0; i < 7; ++i)
            #pragma unroll
            for (int r = 0; r < 4; ++r){
                float v = softplusf(0.5f*t7[i][r] + gy[i][r] + 0.5f*vb[i] + (t0+0.5f)*vw[i] + v1[i]);
                comb[i][r] += v;
            }
        // Hs = comb/12; Hacc += Hs
        #pragma unroll
        for (int i = 0; i < 7; ++i)
            #pragma unroll
            for (int r = 0; r < 4; ++r){
                float v = comb[i][r] * (1.f/12.f);
                comb[i][r] = v;
                hacc[i][r] += v;
            }
        if (st == 0){
            // Gy += Hs@P^T + dt*bvec
            writeA(comb);
            gemmB(Pbf);
            #pragma unroll
            for (int i = 0; i < 7; ++i)
                #pragma unroll
                for (int r = 0; r < 4; ++r) gy[i][r] += t7[i][r] + dt*vb[i];
        }
    }

    // Abf high half = bf16(Hacc)
    #pragma unroll
    for (int i = 0; i < 7; ++i){
        int nt = ng + 4*i;
        if (nt < 25){
            int n = nt*16 + cn;
            #pragma unroll
            for (int r = 0; r < 4; ++r){
                int m = m0 + mt*16 + cm + r;
                Abf[(size_t)m*800 + 400 + n] = f2bf(hacc[i][r]);
            }
        }
    }
}

// ---------------------------------------------------------------------------
// MFMA decode, 256x128 tiles, LDS stride 44.
__global__ __launch_bounds__(512) void decode_mfma_k(
    const unsigned short* __restrict__ Abf,
    const unsigned short* __restrict__ Bbf,
    const float* __restrict__ decb, const float* __restrict__ b2v,
    float* __restrict__ z)
{
    __shared__ unsigned short As[256*44];
    __shared__ unsigned short Bs[128*44];
    int n0 = blockIdx.x*128, m0 = blockIdx.y*256;
    int tid = threadIdx.x;
    int lane = tid & 63, wid = tid >> 6;
    int wr = wid >> 1, wc = wid & 1;
    f32x4 acc[4][4] = {};

    int srA = tid >> 1, skA = (tid & 1)*16;
    int srB = tid >> 2, skB = (tid & 3)*8;

    for (int k0 = 0; k0 < 800; k0 += 32){
        uint4 av0 = {0,0,0,0}, av1 = {0,0,0,0};
        int m = m0 + srA;
        if (m < SB_){
            const uint4* ap = (const uint4*)(Abf + (size_t)m*800 + k0 + skA);
            av0 = ap[0]; av1 = ap[1];
        }
        uint4 bv = *(const uint4*)(Bbf + (size_t)(n0 + srB)*800 + k0 + skB);

        __syncthreads();
        *(uint4*)&As[srA*44 + skA]     = av0;
        *(uint4*)&As[srA*44 + skA + 8] = av1;
        *(uint4*)&Bs[srB*44 + skB]     = bv;
        __syncthreads();

        int kq = (lane >> 4) * 8;
        int rA = wr*64 + (lane & 15);
        int rB = wc*64 + (lane & 15);
        bf16x8 af[4], bfv[4];
        #pragma unroll
        for (int f = 0; f < 4; ++f){
            af[f]  = *(const bf16x8*)&As[(rA + f*16)*44 + kq];
            bfv[f] = *(const bf16x8*)&Bs[(rB + f*16)*44 + kq];
        }
        #pragma unroll
        for (int fm = 0; fm < 4; ++fm)
            #pragma unroll
            for (int fn = 0; fn < 4; ++fn)
                acc[fm][fn] = __builtin_amdgcn_mfma_f32_16x16x32_bf16(af[fm], bfv[fn], acc[fm][fn], 0, 0, 0);
    }

    int cm = (lane >> 4) * 4;
    int cn = lane & 15;
    #pragma unroll
    for (int fm = 0; fm < 4; ++fm){
        int mrow0 = m0 + wr*64 + fm*16 + cm;
        #pragma unroll
        for (int fn = 0; fn < 4; ++fn){
            int n = n0 + wc*64 + fn*16 + cn;
            float db = decb[n] + b2v[n];
            #pragma unroll
            for (int r = 0; r < 4; ++r){
                int mr = mrow0 + r;
                if (mr < SB_) z[(size_t)mr*NT_ + n] = acc[fm][fn][r] + db;
            }
        }
    }
}

// ---------------------------------------------------------------------------
// Fused log-softmax: row resident in registers.
__global__ __launch_bounds__(1024) void softmax_k(float* __restrict__ z)
{
    int r = blockIdx.x;
    float* zr = z + (size_t)r*NT_;
    int tid = threadIdx.x;
    __shared__ float sm[1024];
    float4 v[8];
    float mx = -1e30f;
    #pragma unroll
    for (int i = 0; i < 8; ++i){
        int base = i*4096 + tid*4;
        if (base < NT_){
            v[i] = *(const float4*)(zr + base);
            mx = fmaxf(mx, fmaxf(fmaxf(v[i].x, v[i].y), fmaxf(v[i].z, v[i].w)));
        } else {
            v[i].x = v[i].y = v[i].z = v[i].w = 0.f;
        }
    }
    sm[tid] = mx; __syncthreads();
    for (int s = 512; s > 0; s >>= 1){
        if (tid < s) sm[tid] = fmaxf(sm[tid], sm[tid+s]);
        __syncthreads();
    }
    mx = sm[0]; __syncthreads();
    float sum = 0.f;
    #pragma unroll
    for (int i = 0; i < 8; ++i){
        int base = i*4096 + tid*4;
        if (base < NT_){
            sum += __expf(v[i].x - mx) + __expf(v[i].y - mx)
                 + __expf(v[i].z - mx) + __expf(v[i].w - mx);
        }
    }
    sm[tid] = sum; __syncthreads();
    for (int s = 512; s > 0; s >>= 1){
        if (tid < s) sm[tid] += sm[tid+s];
        __syncthreads();
    }
    float sinv = 1.f / sm[0];
    #pragma unroll
    for (int i = 0; i < 8; ++i){
        int base = i*4096 + tid*4;
        if (base < NT_){
            float4 o;
            o.x = logf(__expf(v[i].x - mx)*sinv + 1e-8f);
            o.y = logf(__expf(v[i].y - mx)*sinv + 1e-8f);
            o.z = logf(__expf(v[i].z - mx)*sinv + 1e-8f);
            o.w = logf(__expf(v[i].w - mx)*sinv + 1e-8f);
            *(float4*)(zr + base) = o;
        }
    }
}

// ---------------------------------------------------------------------------
extern "C" void kernel_launch(void* const* d_in, const int* in_sizes, int n_in,
                              void* d_out, int out_size, void* d_ws, size_t ws_size,
                              hipStream_t stream)
{
    const int*   tokens = (const int*)  d_in[0];
    const float* h0_0 = (const float*)d_in[1];
    const float* c0_0 = (const float*)d_in[2];
    const float* Wih0 = (const float*)d_in[3];
    const float* Whh0 = (const float*)d_in[4];
    const float* bih0 = (const float*)d_in[5];
    const float* bhh0 = (const float*)d_in[6];
    const float* h0_1 = (const float*)d_in[7];
    const float* c0_1 = (const float*)d_in[8];
    const float* Wih1 = (const float*)d_in[9];
    const float* Whh1 = (const float*)d_in[10];
    const float* bih1 = (const float*)d_in[11];
    const float* bhh1 = (const float*)d_in[12];
    const float* h0_2 = (const float*)d_in[13];
    const float* c0_2 = (const float*)d_in[14];
    const float* Wih2 = (const float*)d_in[15];
    const float* Whh2 = (const float*)d_in[16];
    const float* bih2 = (const float*)d_in[17];
    const float* bhh2 = (const float*)d_in[18];
    const float* emb  = (const float*)d_in[19];
    const float* decW = (const float*)d_in[20];
    const float* decb = (const float*)d_in[21];
    const float* odeW1= (const float*)d_in[22];
    const float* odeb1= (const float*)d_in[23];
    const float* odeW2= (const float*)d_in[24];
    const float* odeb2= (const float*)d_in[25];

    // workspace carve-up, all chunks 16B-aligned
    float* w = (float*)d_ws;
    size_t off = 0;
    auto alloc = [&](size_t n){ float* p = w + off; off += n; return p; };
    auto allocU = [&](size_t nUsh){ return (unsigned short*)alloc(nUsh/2); };
    unsigned short* x0A  = allocU((size_t)S_*16*416);
    unsigned short* ys0A = allocU((size_t)S_*16*1152);
    unsigned short* ys1A = allocU((size_t)S_*16*1152);
    float* x3   = alloc((size_t)SB_*400);
    unsigned short* h0b = allocU((size_t)2*16*1152); float* c0b = alloc(1152*16);
    unsigned short* h1b = allocU((size_t)2*16*1152); float* c1b = alloc(1152*16);
    unsigned short* h2b = allocU((size_t)2*16*416);  float* c2b = alloc(416*16);
    unsigned short* Qbf = allocU((size_t)416*416);
    unsigned short* Pbf = allocU((size_t)416*416);
    float* dvec = alloc(512);
    float* bvec = alloc(512);
    float* wtd  = alloc(512);
    float* partials = alloc((size_t)16*320000);
    unsigned short* Wih0p = allocU((size_t)4600*416);
    unsigned short* Whh0p = allocU((size_t)4600*1152);
    unsigned short* Wih1p = allocU((size_t)4600*1152);
    unsigned short* Whh1p = allocU((size_t)4600*1152);
    unsigned short* Wih2p = allocU((size_t)1600*1152);
    unsigned short* Whh2p = allocU((size_t)1600*416);
    unsigned short* Abf   = allocU((size_t)SB_*800);
    unsigned short* Bbf   = allocU((size_t)NT_*800);
    unsigned short* BbfT  = allocU((size_t)800*NT_);
    unsigned short* Wxbf  = allocU((size_t)400*NT_);
    (void)ws_size; (void)in_sizes; (void)n_in; (void)out_size;

    float* zout = (float*)d_out;

    // zero pad-sensitive buffers (MFMA reads pads; must not be NaN)
    hipMemsetAsync(ys0A, 0, (size_t)S_*16*1152*2, stream);
    hipMemsetAsync(ys1A, 0, (size_t)S_*16*1152*2, stream);
    hipMemsetAsync(h0b,  0, (size_t)2*16*1152*2, stream);
    hipMemsetAsync(h1b,  0, (size_t)2*16*1152*2, stream);
    hipMemsetAsync(h2b,  0, (size_t)2*16*416*2, stream);
    hipMemsetAsync(Qbf,  0, (size_t)416*416*2, stream);
    hipMemsetAsync(Pbf,  0, (size_t)416*416*2, stream);

    // weight conversions (bf16, K zero-padded): all six in one launch
    auto cvtgrid = [](long long n){ return (unsigned)((n + 255) / 256); };
    cvt_pack_all_k<<<dim3(cvtgrid((long long)4600*1152), 6), 256, 0, stream>>>(
        Wih0, Wih0p, Whh0, Whh0p, Wih1, Wih1p, Whh1, Whh1p, Wih2, Wih2p, Whh2, Whh2p);
    cvt_catB2_k<<<dim3(500, 25), 256, 0, stream>>>(decW, odeW2, Bbf, BbfT);
    cvt_wx_k<<<cvtgrid((long long)400*NT_), 256, 0, stream>>>(odeW1, Wxbf);

    // activations + state init
    embed_bf_k<<<S_, 256, 0, stream>>>(tokens, emb, x0A);
    cvt_h0_k<<<(16*1150+255)/256, 256, 0, stream>>>(h0_0, h0b, 1150, 1152);
    cvt_h0_k<<<(16*1150+255)/256, 256, 0, stream>>>(h0_1, h1b, 1150, 1152);
    cvt_h0_k<<<(16*400+255)/256,  256, 0, stream>>>(h0_2, h2b, 400, 416);
    transpose16_k<<<(1150*16+255)/256, 256, 0, stream>>>(c0_0, c0b, 1150);
    transpose16_k<<<(1150*16+255)/256, 256, 0, stream>>>(c0_1, c1b, 1150);
    transpose16_k<<<(400*16+255)/256,  256, 0, stream>>>(c0_2, c2b, 400);

    // 3-layer LSTM, layer-pipelined wavefront, MFMA (per-step launches)
    for (int u = 0; u < S_ + 2; ++u)
        lstm_mfma_k<<<169, 1024, 0, stream>>>(u, x0A, ys0A, ys1A, x3,
            h0b, c0b, h1b, c1b, h2b, c2b,
            Wih0p, Whh0p, bih0, bhh0, Wih1p, Whh1p, bih1, bhh1, Wih2p, Whh2p, bih2, bhh2);

    // ODE factorization precompute: [Q|P] = Wx @ BbfT^T via MFMA, 16 K-slabs
    vecs_k<<<400, 256, 0, stream>>>(Wxbf, odeW1, decb, odeb2, dvec, bvec, wtd);
    gemm_odeT_k<<<dim3(7,4,16), 256, 0, stream>>>(Wxbf, BbfT, partials);
    reduce16bf_k<<<(320000+255)/256, 256, 0, stream>>>(partials, Qbf, Pbf);

    // Fused ODE: G0 + RK4(2 steps) + Abf (both halves) in one kernel
    ode_rk4_k<<<35, 512, 0, stream>>>(x3, Qbf, Pbf, dvec, bvec, wtd, odeb1, Abf);

    // MFMA decode (256x128 tiles) + fused log-softmax
    decode_mfma_k<<<dim3(250,5), 512, 0, stream>>>(Abf, Bbf, decb, odeb2, zout);
    softmax_k<<<SB_, 1024, 0, stream>>>(zout);
}

// Round 10
// 1970.558 us; speedup vs baseline: 5.1471x; 1.0442x over previous
//
#include <hip/hip_runtime.h>
#include <math.h>

// Problem dims
constexpr int S_   = 70;
constexpr int B_   = 16;
constexpr int SB_  = 1120;     // S*B
constexpr int NT_  = 32000;    // NTOKEN
constexpr int W1S_ = 32001;    // odeW1 row stride (NTOKEN+1)
constexpr int AST  = 424;      // ode kernel LDS A stride (ushorts)

typedef __attribute__((ext_vector_type(8))) short bf16x8;
typedef __attribute__((ext_vector_type(4))) float f32x4;

__device__ __forceinline__ float sigm(float x){ return 1.f/(1.f+__expf(-x)); }
__device__ __forceinline__ float softplusf(float x){ return x > 15.f ? x : log1pf(__expf(x)); }

__device__ __forceinline__ unsigned short f2bf(float f){
    union{float f; unsigned u;} c; c.f = f;
    unsigned u = c.u;
    unsigned r = (u + 0x7fffu + ((u >> 16) & 1u)) >> 16;
    return (unsigned short)r;
}
__device__ __forceinline__ float bfu(unsigned short us){
    union{unsigned u; float f;} c; c.u = ((unsigned)us) << 16; return c.f;
}

// ---------------------------------------------------------------------------
// All six LSTM weight conversions in one launch: fp32 [R][K] -> bf16 [R][Kp]
__global__ __launch_bounds__(256) void cvt_pack_all_k(
    const float* __restrict__ s0, unsigned short* __restrict__ d0,
    const float* __restrict__ s1, unsigned short* __restrict__ d1,
    const float* __restrict__ s2, unsigned short* __restrict__ d2,
    const float* __restrict__ s3, unsigned short* __restrict__ d3,
    const float* __restrict__ s4, unsigned short* __restrict__ d4,
    const float* __restrict__ s5, unsigned short* __restrict__ d5)
{
    int seg = blockIdx.y;
    const float* src; unsigned short* dst; int R, K, Kp;
    switch(seg){
      case 0: src=s0; dst=d0; R=4600; K=400;  Kp=416;  break;
      case 1: src=s1; dst=d1; R=4600; K=1150; Kp=1152; break;
      case 2: src=s2; dst=d2; R=4600; K=1150; Kp=1152; break;
      case 3: src=s3; dst=d3; R=4600; K=1150; Kp=1152; break;
      case 4: src=s4; dst=d4; R=1600; K=1150; Kp=1152; break;
      default:src=s5; dst=d5; R=1600; K=400;  Kp=416;  break;
    }
    long long idx = (long long)blockIdx.x*256 + threadIdx.x;
    long long tot = (long long)R*Kp;
    if (idx >= tot) return;
    int r = (int)(idx / Kp), kk = (int)(idx - (long long)r*Kp);
    float v = (kk < K) ? src[(size_t)r*K + kk] : 0.f;
    dst[idx] = f2bf(v);
}

// Fused: Bbf[32000][800] row-major AND BbfT[800][32000] transposed, single read.
__global__ __launch_bounds__(256) void cvt_catB2_k(const float* __restrict__ decW,
                                                   const float* __restrict__ odeW2,
                                                   unsigned short* __restrict__ Bbf,
                                                   unsigned short* __restrict__ BbfT)
{
    __shared__ unsigned short tile[32][72];
    int v0 = blockIdx.x*64, n0 = blockIdx.y*32;
    int tx = threadIdx.x & 31;
    int vy = threadIdx.x >> 5;
    #pragma unroll
    for (int i = 0; i < 8; ++i){
        int v = v0 + i*8 + vy;
        int n = n0 + tx;
        float val = (n < 400) ? decW[(size_t)v*400 + n] : odeW2[(size_t)v*400 + (n-400)];
        unsigned short us = f2bf(val);
        tile[tx][v - v0] = us;
        Bbf[(size_t)v*800 + n] = us;
    }
    __syncthreads();
    int vx = threadIdx.x & 63;
    int ny = threadIdx.x >> 6;
    #pragma unroll
    for (int i = 0; i < 8; ++i){
        int n = n0 + i*4 + ny;
        BbfT[(size_t)n*NT_ + v0 + vx] = tile[n - n0][vx];
    }
}

// Wxbf[400][32000] = bf16(odeW1[:,1:])
__global__ __launch_bounds__(256) void cvt_wx_k(const float* __restrict__ odeW1,
                                                unsigned short* __restrict__ Wxbf)
{
    long long idx = (long long)blockIdx.x*256 + threadIdx.x;
    if (idx >= (long long)400*NT_) return;
    int m = (int)(idx / NT_), v = (int)(idx - (long long)m*NT_);
    Wxbf[idx] = f2bf(odeW1[(size_t)m*W1S_ + 1 + v]);
}

// ---------------------------------------------------------------------------
// Embedding gather -> bf16 A-layout: x0A[t][b][k] (stride 416, zero-padded)
__global__ __launch_bounds__(256) void embed_bf_k(const int* __restrict__ tok,
                                                  const float* __restrict__ emb,
                                                  unsigned short* __restrict__ x0A)
{
    int t = blockIdx.x;
    __shared__ int tk[16];
    if (threadIdx.x < 16) tk[threadIdx.x] = tok[t*16 + threadIdx.x];
    __syncthreads();
    for (int idx = threadIdx.x; idx < 16*416; idx += 256){
        int b = idx / 416, k = idx - b*416;
        float v = (k < 400) ? emb[(size_t)tk[b]*400 + k] : 0.f;
        x0A[(size_t)t*16*416 + idx] = f2bf(v);
    }
}

// dst[j*16+b] = src[b*dh+j]  (c-state init)
__global__ __launch_bounds__(256) void transpose16_k(const float* __restrict__ src,
                                                     float* __restrict__ dst, int dh)
{
    int idx = blockIdx.x*256 + threadIdx.x;
    if (idx < dh*16){ int j = idx >> 4, b = idx & 15; dst[idx] = src[b*dh + j]; }
}

// h0 [16][Dh] fp32 -> hb [16][SA] bf16
__global__ __launch_bounds__(256) void cvt_h0_k(const float* __restrict__ h0,
                                                unsigned short* __restrict__ hb, int Dh, int SA)
{
    int idx = blockIdx.x*256 + threadIdx.x;
    if (idx >= 16*Dh) return;
    int b = idx / Dh, j = idx - b*Dh;
    hb[(size_t)b*SA + j] = f2bf(h0[idx]);
}

// ---------------------------------------------------------------------------
// K-segment dot with 4 accumulator chains.
__device__ __forceinline__ void dotseg(const unsigned short* __restrict__ a,
                                       const unsigned short* __restrict__ b,
                                       int s, int e, int kq,
                                       f32x4& c0, f32x4& c1, f32x4& c2, f32x4& c3)
{
    int k0 = s;
    for (; k0 + 128 <= e; k0 += 128){
        bf16x8 a0 = *(const bf16x8*)(a + k0 + kq);
        bf16x8 b0 = *(const bf16x8*)(b + k0 + kq);
        bf16x8 a1 = *(const bf16x8*)(a + k0 + 32 + kq);
        bf16x8 b1 = *(const bf16x8*)(b + k0 + 32 + kq);
        bf16x8 a2 = *(const bf16x8*)(a + k0 + 64 + kq);
        bf16x8 b2 = *(const bf16x8*)(b + k0 + 64 + kq);
        bf16x8 a3 = *(const bf16x8*)(a + k0 + 96 + kq);
        bf16x8 b3 = *(const bf16x8*)(b + k0 + 96 + kq);
        c0 = __builtin_amdgcn_mfma_f32_16x16x32_bf16(a0, b0, c0, 0,0,0);
        c1 = __builtin_amdgcn_mfma_f32_16x16x32_bf16(a1, b1, c1, 0,0,0);
        c2 = __builtin_amdgcn_mfma_f32_16x16x32_bf16(a2, b2, c2, 0,0,0);
        c3 = __builtin_amdgcn_mfma_f32_16x16x32_bf16(a3, b3, c3, 0,0,0);
    }
    int rem = e - k0;
    if (rem >= 32){
        bf16x8 a0 = *(const bf16x8*)(a + k0 + kq);
        bf16x8 b0 = *(const bf16x8*)(b + k0 + kq);
        c0 = __builtin_amdgcn_mfma_f32_16x16x32_bf16(a0, b0, c0, 0,0,0);
    }
    if (rem >= 64){
        bf16x8 a1 = *(const bf16x8*)(a + k0 + 32 + kq);
        bf16x8 b1 = *(const bf16x8*)(b + k0 + 32 + kq);
        c1 = __builtin_amdgcn_mfma_f32_16x16x32_bf16(a1, b1, c1, 0,0,0);
    }
    if (rem >= 96){
        bf16x8 a2 = *(const bf16x8*)(a + k0 + 64 + kq);
        bf16x8 b2 = *(const bf16x8*)(b + k0 + 64 + kq);
        c2 = __builtin_amdgcn_mfma_f32_16x16x32_bf16(a2, b2, c2, 0,0,0);
    }
}

// One wavefront step of the 3-layer LSTM pipeline, MFMA, 4-way K-split.
// Block = one 16-unit j-tile; 16 waves = 4 gates x 4 K-quarters (1024 threads).
__global__ __launch_bounds__(1024) void lstm_mfma_k(int u,
    const unsigned short* __restrict__ x0A,
    unsigned short* __restrict__ ys0A, unsigned short* __restrict__ ys1A,
    float* __restrict__ x3,
    unsigned short* __restrict__ h0b, float* __restrict__ c0,
    unsigned short* __restrict__ h1b, float* __restrict__ c1,
    unsigned short* __restrict__ h2b, float* __restrict__ c2,
    const unsigned short* __restrict__ Wih0p, const unsigned short* __restrict__ Whh0p,
    const float* __restrict__ bih0, const float* __restrict__ bhh0,
    const unsigned short* __restrict__ Wih1p, const unsigned short* __restrict__ Whh1p,
    const float* __restrict__ bih1, const float* __restrict__ bhh1,
    const unsigned short* __restrict__ Wih2p, const unsigned short* __restrict__ Whh2p,
    const float* __restrict__ bih2, const float* __restrict__ bhh2)
{
    int blk = blockIdx.x;
    int layer, jt;
    if      (blk < 72) { layer = 0; jt = blk; }
    else if (blk < 144){ layer = 1; jt = blk - 72; }
    else               { layer = 2; jt = blk - 144; }
    int t = u - layer;
    if (t < 0 || t >= S_) return;
    int j0 = jt*16;

    const unsigned short *Ax, *Ah, *Wi, *Wh;
    const float *bih, *bhh;
    float *cst, *x3o = nullptr;
    unsigned short *yo = nullptr, *hrec;
    int Kx, Kh, Dh, SAx, SAh;
    if (layer == 0){
        Ax = x0A + (size_t)t*16*416; SAx = 416; Kx = 416;
        Ah = h0b + (size_t)(t&1)*16*1152; SAh = 1152; Kh = 1152;
        Wi = Wih0p; Wh = Whh0p; bih = bih0; bhh = bhh0; Dh = 1150;
        cst = c0; hrec = h0b + (size_t)((t+1)&1)*16*1152;
        yo = ys0A + (size_t)t*16*1152;
    } else if (layer == 1){
        Ax = ys0A + (size_t)t*16*1152; SAx = 1152; Kx = 1152;
        Ah = h1b + (size_t)(t&1)*16*1152; SAh = 1152; Kh = 1152;
        Wi = Wih1p; Wh = Whh1p; bih = bih1; bhh = bhh1; Dh = 1150;
        cst = c1; hrec = h1b + (size_t)((t+1)&1)*16*1152;
        yo = ys1A + (size_t)t*16*1152;
    } else {
        Ax = ys1A + (size_t)t*16*1152; SAx = 1152; Kx = 1152;
        Ah = h2b + (size_t)(t&1)*16*416; SAh = 416; Kh = 416;
        Wi = Wih2p; Wh = Whh2p; bih = bih2; bhh = bhh2; Dh = 400;
        cst = c2; hrec = h2b + (size_t)((t+1)&1)*16*416;
        x3o = x3 + (size_t)t*16*400;
    }

    int lane = threadIdx.x & 63, w = threadIdx.x >> 6;   // w = 0..15
    int gate = w & 3, kq4 = w >> 2;
    int am = lane & 15;
    int kq = (lane >> 4) * 8;
    int jn = lane & 15;
    int jrow = j0 + jn; if (jrow > Dh-1) jrow = Dh-1;

    const unsigned short* ax = Ax + (size_t)am*SAx;
    const unsigned short* ah = Ah + (size_t)am*SAh;
    const unsigned short* wx = Wi + (size_t)(gate*Dh + jrow)*SAx;
    const unsigned short* wh = Wh + (size_t)(gate*Dh + jrow)*SAh;

    int nx = Kx >> 5, nh = Kh >> 5;
    int xq0 = ((nx *  kq4     ) >> 2) << 5;
    int xq1 = ((nx * (kq4 + 1)) >> 2) << 5;
    int hq0 = ((nh *  kq4     ) >> 2) << 5;
    int hq1 = ((nh * (kq4 + 1)) >> 2) << 5;

    f32x4 c0v = {0.f,0.f,0.f,0.f}, c1v = {0.f,0.f,0.f,0.f};
    f32x4 c2v = {0.f,0.f,0.f,0.f}, c3v = {0.f,0.f,0.f,0.f};
    dotseg(ax, wx, xq0, xq1, kq, c0v, c1v, c2v, c3v);
    dotseg(ah, wh, hq0, hq1, kq, c0v, c1v, c2v, c3v);
    f32x4 acc = (c0v + c1v) + (c2v + c3v);

    __shared__ float g16[16][16][17];
    int bm = (lane >> 4) * 4;
    #pragma unroll
    for (int r = 0; r < 4; ++r) g16[w][bm + r][jn] = acc[r];
    __syncthreads();

    if (threadIdx.x < 256){
        int jl = threadIdx.x >> 4, b = threadIdx.x & 15;
        int j = j0 + jl;
        if (j < Dh){
            float pi = g16[0][b][jl] + g16[4][b][jl] + g16[8][b][jl]  + g16[12][b][jl] + bih[j]      + bhh[j];
            float pf = g16[1][b][jl] + g16[5][b][jl] + g16[9][b][jl]  + g16[13][b][jl] + bih[Dh+j]   + bhh[Dh+j];
            float pg = g16[2][b][jl] + g16[6][b][jl] + g16[10][b][jl] + g16[14][b][jl] + bih[2*Dh+j] + bhh[2*Dh+j];
            float po = g16[3][b][jl] + g16[7][b][jl] + g16[11][b][jl] + g16[15][b][jl] + bih[3*Dh+j] + bhh[3*Dh+j];
            float cold = cst[j*16 + b];
            float cnew = sigm(pf)*cold + sigm(pi)*tanhf(pg);
            float h    = sigm(po)*tanhf(cnew);
            cst[j*16 + b] = cnew;
            unsigned short hb16 = f2bf(h);
            hrec[(size_t)b*SAh + j] = hb16;
            if (yo)  yo[(size_t)b*1152 + j] = hb16;
            if (x3o) x3o[(size_t)b*400 + j] = h;
        }
    }
}

// ---------------------------------------------------------------------------
// dvec[j] = Wx[j,:]·decb ; bvec[j] = Wx[j,:]·b2 ; wtd[j] = odeW1[j,0]
__global__ __launch_bounds__(256) void vecs_k(const unsigned short* __restrict__ Wxbf,
                                              const float* __restrict__ odeW1,
                                              const float* __restrict__ decb,
                                              const float* __restrict__ b2v,
                                              float* __restrict__ dvec,
                                              float* __restrict__ bvec,
                                              float* __restrict__ wtd)
{
    int jrow = blockIdx.x;
    __shared__ float r1[256], r2[256];
    const unsigned short* wx = Wxbf + (size_t)jrow*NT_;
    float s1 = 0.f, s2 = 0.f;
    for (int v = threadIdx.x; v < NT_; v += 256){
        float w = bfu(wx[v]); s1 += w*decb[v]; s2 += w*b2v[v];
    }
    r1[threadIdx.x] = s1; r2[threadIdx.x] = s2; __syncthreads();
    for (int s = 128; s > 0; s >>= 1){
        if (threadIdx.x < s){ r1[threadIdx.x] += r1[threadIdx.x+s]; r2[threadIdx.x] += r2[threadIdx.x+s]; }
        __syncthreads();
    }
    if (threadIdx.x == 0){ dvec[jrow] = r1[0]; bvec[jrow] = r2[0]; wtd[jrow] = odeW1[(size_t)jrow*W1S_]; }
}

// ---------------------------------------------------------------------------
// MFMA ODE precompute, LDS stride 44, 16 K-slabs.
__global__ __launch_bounds__(256) void gemm_odeT_k(
    const unsigned short* __restrict__ Wxbf,
    const unsigned short* __restrict__ BbfT,
    float* __restrict__ partials)
{
    __shared__ unsigned short As[128*44];
    __shared__ unsigned short Bs[128*44];
    int n0 = blockIdx.x*128, m0 = blockIdx.y*128, v0 = blockIdx.z*2000;
    int tid = threadIdx.x;
    int lane = tid & 63, wid = tid >> 6;
    int wr = wid >> 1, wc = wid & 1;
    f32x4 acc[4][4] = {};

    int srow = tid >> 1;
    int sk   = (tid & 1) * 16;
    int mL = m0 + srow; if (mL > 399) mL = 399;
    int nL = n0 + srow; if (nL > 799) nL = 799;
    const unsigned short* ap = Wxbf + (size_t)mL*NT_ + v0 + sk;
    const unsigned short* bp = BbfT + (size_t)nL*NT_ + v0 + sk;

    for (int k0 = 0; k0 < 2000; k0 += 32){
        uint4 av0 = *(const uint4*)(ap + k0);
        uint4 av1 = *(const uint4*)(ap + k0 + 8);
        uint4 bv0 = *(const uint4*)(bp + k0);
        uint4 bv1 = *(const uint4*)(bp + k0 + 8);

        __syncthreads();
        *(uint4*)&As[srow*44 + sk]     = av0;
        *(uint4*)&As[srow*44 + sk + 8] = av1;
        *(uint4*)&Bs[srow*44 + sk]     = bv0;
        *(uint4*)&Bs[srow*44 + sk + 8] = bv1;
        __syncthreads();

        int kq = (lane >> 4) * 8;
        int rA = wr*64 + (lane & 15);
        int rB = wc*64 + (lane & 15);
        bf16x8 af[4], bfv[4];
        #pragma unroll
        for (int f = 0; f < 4; ++f){
            af[f]  = *(const bf16x8*)&As[(rA + f*16)*44 + kq];
            bfv[f] = *(const bf16x8*)&Bs[(rB + f*16)*44 + kq];
        }
        #pragma unroll
        for (int fm = 0; fm < 4; ++fm)
            #pragma unroll
            for (int fn = 0; fn < 4; ++fn)
                acc[fm][fn] = __builtin_amdgcn_mfma_f32_16x16x32_bf16(af[fm], bfv[fn], acc[fm][fn], 0, 0, 0);
    }

    float* op = partials + (size_t)blockIdx.z*320000;
    int cm = (lane >> 4) * 4;
    int cn = lane & 15;
    #pragma unroll
    for (int fm = 0; fm < 4; ++fm){
        int mrow0 = m0 + wr*64 + fm*16 + cm;
        #pragma unroll
        for (int fn = 0; fn < 4; ++fn){
            int n = n0 + wc*64 + fn*16 + cn;
            if (n >= 800) continue;
            #pragma unroll
            for (int r = 0; r < 4; ++r){
                int mr = mrow0 + r;
                if (mr < 400) op[mr*800 + n] = acc[fm][fn][r];
            }
        }
    }
}

// sum 16 slabs; scatter to PADDED bf16 [416][416] (rows/cols >=400 stay zero)
__global__ __launch_bounds__(256) void reduce16bf_k(const float* __restrict__ p,
                                                    unsigned short* __restrict__ Qbf,
                                                    unsigned short* __restrict__ Pbf)
{
    int i = blockIdx.x*256 + threadIdx.x;
    if (i >= 320000) return;
    float s = 0.f;
    #pragma unroll
    for (int k = 0; k < 16; ++k) s += p[(size_t)k*320000 + i];
    int m = i / 800, n = i - m*800;
    if (n < 400) Qbf[m*416 + n] = f2bf(s);
    else         Pbf[m*416 + (n-400)] = f2bf(s);
}

// ---------------------------------------------------------------------------
// FUSED ODE: G0 GEMM + 2 RK4 steps + Gy update + Abf output.
// Block = 16 G-rows (70 blocks); 8 waves = 8 n-groups; thread owns 4 n-tiles
// (nt = ng + 8*i) -> per-thread arrays [4][4]: no VGPR spill (round-9 fix).
__global__ __launch_bounds__(512) void ode_rk4_k(
    const float* __restrict__ x3,
    const unsigned short* __restrict__ Qbf,
    const unsigned short* __restrict__ Pbf,
    const float* __restrict__ dvec, const float* __restrict__ bvec,
    const float* __restrict__ wtd, const float* __restrict__ b1,
    unsigned short* __restrict__ Abf)
{
    __shared__ unsigned short Al[16*AST];
    int m0 = blockIdx.x*16;
    int tid = threadIdx.x;
    int lane = tid & 63, ng = tid >> 6;   // 8 n-groups
    int cm = (lane >> 4)*4;
    int cn = lane & 15;
    int kq = (lane >> 4)*8;

    // initial A = bf16(x3 rows); also global Abf low half (16*400 = 6400)
    #pragma unroll
    for (int i = 0; i < 13; ++i){
        int idx = i*512 + tid;
        if (idx < 6400){
            int m = idx / 400, k = idx - m*400;
            unsigned short us = f2bf(x3[(size_t)(m0+m)*400 + k]);
            Al[m*AST + k] = us;
            Abf[(size_t)(m0+m)*800 + k] = us;
        }
    }
    if (tid < 256){ Al[(tid>>4)*AST + 400 + (tid & 15)] = 0; }  // zero K-pad
    __syncthreads();

    float gy[4][4], hacc[4][4], comb[4][4];
    float vd[4], vb[4], vw[4], v1[4];
    #pragma unroll
    for (int i = 0; i < 4; ++i){
        int nt = ng + 8*i;
        if (nt < 25){
            int n = nt*16 + cn;
            vd[i] = dvec[n]; vb[i] = bvec[n]; vw[i] = wtd[n]; v1[i] = b1[n];
        } else { vd[i]=0.f; vb[i]=0.f; vw[i]=0.f; v1[i]=0.f; }
        #pragma unroll
        for (int r = 0; r < 4; ++r) hacc[i][r] = 0.f;
    }

    const unsigned short* arow = &Al[(size_t)cn*AST + kq];
    f32x4 t4[4];
    auto gemmB = [&](const unsigned short* Bb){
        #pragma unroll
        for (int i = 0; i < 4; ++i){
            f32x4 a = {0.f,0.f,0.f,0.f};
            int nt = ng + 8*i;
            if (nt < 25){
                const unsigned short* brow = Bb + (size_t)(nt*16 + cn)*416 + kq;
                #pragma unroll
                for (int k0 = 0; k0 < 416; k0 += 32){
                    bf16x8 av = *(const bf16x8*)(arow + k0);
                    bf16x8 bv = *(const bf16x8*)(brow + k0);
                    a = __builtin_amdgcn_mfma_f32_16x16x32_bf16(av, bv, a, 0,0,0);
                }
            }
            t4[i] = a;
        }
    };
    // write fragment values (as bf16) into Al as next A operand
    auto writeA = [&](float vals[4][4]){
        __syncthreads();   // all waves done reading Al
        #pragma unroll
        for (int i = 0; i < 4; ++i){
            int nt = ng + 8*i;
            if (nt < 25){
                int n = nt*16 + cn;
                #pragma unroll
                for (int r = 0; r < 4; ++r)
                    Al[(cm + r)*AST + n] = f2bf(vals[i][r]);
            }
        }
        __syncthreads();
    };

    // G0 = x3 @ Q^T + dvec
    gemmB(Qbf);
    #pragma unroll
    for (int i = 0; i < 4; ++i)
        #pragma unroll
        for (int r = 0; r < 4; ++r) gy[i][r] = t4[i][r] + vd[i];

    const float dt = 0.5f;
    for (int st = 0; st < 2; ++st){
        float t0 = st * dt;
        float hs[4][4];
        // H1 = softplus(Gy + t0*wt + b1)
        #pragma unroll
        for (int i = 0; i < 4; ++i)
            #pragma unroll
            for (int r = 0; r < 4; ++r){
                float v = softplusf(gy[i][r] + t0*vw[i] + v1[i]);
                hs[i][r] = v; comb[i][r] = v;
            }
        writeA(hs);
        // H2: coef 0.25, weight 2
        gemmB(Pbf);
        #pragma unroll
        for (int i = 0; i < 4; ++i)
            #pragma unroll
            for (int r = 0; r < 4; ++r){
                float v = softplusf(0.25f*t4[i][r] + gy[i][r] + 0.25f*vb[i] + (t0+0.25f)*vw[i] + v1[i]);
                hs[i][r] = v; comb[i][r] += 2.f*v;
            }
        writeA(hs);
        // H3: coef 0.25, weight 2
        gemmB(Pbf);
        #pragma unroll
        for (int i = 0; i < 4; ++i)
            #pragma unroll
            for (int r = 0; r < 4; ++r){
                float v = softplusf(0.25f*t4[i][r] + gy[i][r] + 0.25f*vb[i] + (t0+0.25f)*vw[i] + v1[i]);
                hs[i][r] = v; comb[i][r] += 2.f*v;
            }
        writeA(hs);
        // H4: coef 0.5, weight 1
        gemmB(Pbf);
        #pragma unroll
        for (int i = 0; i < 4; ++i)
            #pragma unroll
            for (int r = 0; r < 4; ++r){
                float v = softplusf(0.5f*t4[i][r] + gy[i][r] + 0.5f*vb[i] + (t0+0.5f)*vw[i] + v1[i]);
                comb[i][r] += v;
            }
        // Hs = comb/12; Hacc += Hs
        #pragma unroll
        for (int i = 0; i < 4; ++i)
            #pragma unroll
            for (int r = 0; r < 4; ++r){
                float v = comb[i][r] * (1.f/12.f);
                comb[i][r] = v;
                hacc[i][r] += v;
            }
        if (st == 0){
            // Gy += Hs@P^T + dt*bvec
            writeA(comb);
            gemmB(Pbf);
            #pragma unroll
            for (int i = 0; i < 4; ++i)
                #pragma unroll
                for (int r = 0; r < 4; ++r) gy[i][r] += t4[i][r] + dt*vb[i];
        }
    }

    // Abf high half = bf16(Hacc)
    #pragma unroll
    for (int i = 0; i < 4; ++i){
        int nt = ng + 8*i;
        if (nt < 25){
            int n = nt*16 + cn;
            #pragma unroll
            for (int r = 0; r < 4; ++r){
                int m = m0 + cm + r;
                Abf[(size_t)m*800 + 400 + n] = f2bf(hacc[i][r]);
            }
        }
    }
}

// ---------------------------------------------------------------------------
// MFMA decode, 256x128 tiles, LDS stride 44.
__global__ __launch_bounds__(512) void decode_mfma_k(
    const unsigned short* __restrict__ Abf,
    const unsigned short* __restrict__ Bbf,
    const float* __restrict__ decb, const float* __restrict__ b2v,
    float* __restrict__ z)
{
    __shared__ unsigned short As[256*44];
    __shared__ unsigned short Bs[128*44];
    int n0 = blockIdx.x*128, m0 = blockIdx.y*256;
    int tid = threadIdx.x;
    int lane = tid & 63, wid = tid >> 6;
    int wr = wid >> 1, wc = wid & 1;
    f32x4 acc[4][4] = {};

    int srA = tid >> 1, skA = (tid & 1)*16;
    int srB = tid >> 2, skB = (tid & 3)*8;

    for (int k0 = 0; k0 < 800; k0 += 32){
        uint4 av0 = {0,0,0,0}, av1 = {0,0,0,0};
        int m = m0 + srA;
        if (m < SB_){
            const uint4* ap = (const uint4*)(Abf + (size_t)m*800 + k0 + skA);
            av0 = ap[0]; av1 = ap[1];
        }
        uint4 bv = *(const uint4*)(Bbf + (size_t)(n0 + srB)*800 + k0 + skB);

        __syncthreads();
        *(uint4*)&As[srA*44 + skA]     = av0;
        *(uint4*)&As[srA*44 + skA + 8] = av1;
        *(uint4*)&Bs[srB*44 + skB]     = bv;
        __syncthreads();

        int kq = (lane >> 4) * 8;
        int rA = wr*64 + (lane & 15);
        int rB = wc*64 + (lane & 15);
        bf16x8 af[4], bfv[4];
        #pragma unroll
        for (int f = 0; f < 4; ++f){
            af[f]  = *(const bf16x8*)&As[(rA + f*16)*44 + kq];
            bfv[f] = *(const bf16x8*)&Bs[(rB + f*16)*44 + kq];
        }
        #pragma unroll
        for (int fm = 0; fm < 4; ++fm)
            #pragma unroll
            for (int fn = 0; fn < 4; ++fn)
                acc[fm][fn] = __builtin_amdgcn_mfma_f32_16x16x32_bf16(af[fm], bfv[fn], acc[fm][fn], 0, 0, 0);
    }

    int cm = (lane >> 4) * 4;
    int cn = lane & 15;
    #pragma unroll
    for (int fm = 0; fm < 4; ++fm){
        int mrow0 = m0 + wr*64 + fm*16 + cm;
        #pragma unroll
        for (int fn = 0; fn < 4; ++fn){
            int n = n0 + wc*64 + fn*16 + cn;
            float db = decb[n] + b2v[n];
            #pragma unroll
            for (int r = 0; r < 4; ++r){
                int mr = mrow0 + r;
                if (mr < SB_) z[(size_t)mr*NT_ + n] = acc[fm][fn][r] + db;
            }
        }
    }
}

// ---------------------------------------------------------------------------
// Fused log-softmax: row resident in registers.
__global__ __launch_bounds__(1024) void softmax_k(float* __restrict__ z)
{
    int r = blockIdx.x;
    float* zr = z + (size_t)r*NT_;
    int tid = threadIdx.x;
    __shared__ float sm[1024];
    float4 v[8];
    float mx = -1e30f;
    #pragma unroll
    for (int i = 0; i < 8; ++i){
        int base = i*4096 + tid*4;
        if (base < NT_){
            v[i] = *(const float4*)(zr + base);
            mx = fmaxf(mx, fmaxf(fmaxf(v[i].x, v[i].y), fmaxf(v[i].z, v[i].w)));
        } else {
            v[i].x = v[i].y = v[i].z = v[i].w = 0.f;
        }
    }
    sm[tid] = mx; __syncthreads();
    for (int s = 512; s > 0; s >>= 1){
        if (tid < s) sm[tid] = fmaxf(sm[tid], sm[tid+s]);
        __syncthreads();
    }
    mx = sm[0]; __syncthreads();
    float sum = 0.f;
    #pragma unroll
    for (int i = 0; i < 8; ++i){
        int base = i*4096 + tid*4;
        if (base < NT_){
            sum += __expf(v[i].x - mx) + __expf(v[i].y - mx)
                 + __expf(v[i].z - mx) + __expf(v[i].w - mx);
        }
    }
    sm[tid] = sum; __syncthreads();
    for (int s = 512; s > 0; s >>= 1){
        if (tid < s) sm[tid] += sm[tid+s];
        __syncthreads();
    }
    float sinv = 1.f / sm[0];
    #pragma unroll
    for (int i = 0; i < 8; ++i){
        int base = i*4096 + tid*4;
        if (base < NT_){
            float4 o;
            o.x = logf(__expf(v[i].x - mx)*sinv + 1e-8f);
            o.y = logf(__expf(v[i].y - mx)*sinv + 1e-8f);
            o.z = logf(__expf(v[i].z - mx)*sinv + 1e-8f);
            o.w = logf(__expf(v[i].w - mx)*sinv + 1e-8f);
            *(float4*)(zr + base) = o;
        }
    }
}

// ---------------------------------------------------------------------------
extern "C" void kernel_launch(void* const* d_in, const int* in_sizes, int n_in,
                              void* d_out, int out_size, void* d_ws, size_t ws_size,
                              hipStream_t stream)
{
    const int*   tokens = (const int*)  d_in[0];
    const float* h0_0 = (const float*)d_in[1];
    const float* c0_0 = (const float*)d_in[2];
    const float* Wih0 = (const float*)d_in[3];
    const float* Whh0 = (const float*)d_in[4];
    const float* bih0 = (const float*)d_in[5];
    const float* bhh0 = (const float*)d_in[6];
    const float* h0_1 = (const float*)d_in[7];
    const float* c0_1 = (const float*)d_in[8];
    const float* Wih1 = (const float*)d_in[9];
    const float* Whh1 = (const float*)d_in[10];
    const float* bih1 = (const float*)d_in[11];
    const float* bhh1 = (const float*)d_in[12];
    const float* h0_2 = (const float*)d_in[13];
    const float* c0_2 = (const float*)d_in[14];
    const float* Wih2 = (const float*)d_in[15];
    const float* Whh2 = (const float*)d_in[16];
    const float* bih2 = (const float*)d_in[17];
    const float* bhh2 = (const float*)d_in[18];
    const float* emb  = (const float*)d_in[19];
    const float* decW = (const float*)d_in[20];
    const float* decb = (const float*)d_in[21];
    const float* odeW1= (const float*)d_in[22];
    const float* odeb1= (const float*)d_in[23];
    const float* odeW2= (const float*)d_in[24];
    const float* odeb2= (const float*)d_in[25];

    // workspace carve-up, all chunks 16B-aligned
    float* w = (float*)d_ws;
    size_t off = 0;
    auto alloc = [&](size_t n){ float* p = w + off; off += n; return p; };
    auto allocU = [&](size_t nUsh){ return (unsigned short*)alloc(nUsh/2); };
    unsigned short* x0A  = allocU((size_t)S_*16*416);
    unsigned short* ys0A = allocU((size_t)S_*16*1152);
    unsigned short* ys1A = allocU((size_t)S_*16*1152);
    float* x3   = alloc((size_t)SB_*400);
    unsigned short* h0b = allocU((size_t)2*16*1152); float* c0b = alloc(1152*16);
    unsigned short* h1b = allocU((size_t)2*16*1152); float* c1b = alloc(1152*16);
    unsigned short* h2b = allocU((size_t)2*16*416);  float* c2b = alloc(416*16);
    unsigned short* Qbf = allocU((size_t)416*416);
    unsigned short* Pbf = allocU((size_t)416*416);
    float* dvec = alloc(512);
    float* bvec = alloc(512);
    float* wtd  = alloc(512);
    float* partials = alloc((size_t)16*320000);
    unsigned short* Wih0p = allocU((size_t)4600*416);
    unsigned short* Whh0p = allocU((size_t)4600*1152);
    unsigned short* Wih1p = allocU((size_t)4600*1152);
    unsigned short* Whh1p = allocU((size_t)4600*1152);
    unsigned short* Wih2p = allocU((size_t)1600*1152);
    unsigned short* Whh2p = allocU((size_t)1600*416);
    unsigned short* Abf   = allocU((size_t)SB_*800);
    unsigned short* Bbf   = allocU((size_t)NT_*800);
    unsigned short* BbfT  = allocU((size_t)800*NT_);
    unsigned short* Wxbf  = allocU((size_t)400*NT_);
    (void)ws_size; (void)in_sizes; (void)n_in; (void)out_size;

    float* zout = (float*)d_out;

    // zero pad-sensitive buffers (MFMA reads pads; must not be NaN)
    hipMemsetAsync(ys0A, 0, (size_t)S_*16*1152*2, stream);
    hipMemsetAsync(ys1A, 0, (size_t)S_*16*1152*2, stream);
    hipMemsetAsync(h0b,  0, (size_t)2*16*1152*2, stream);
    hipMemsetAsync(h1b,  0, (size_t)2*16*1152*2, stream);
    hipMemsetAsync(h2b,  0, (size_t)2*16*416*2, stream);
    hipMemsetAsync(Qbf,  0, (size_t)416*416*2, stream);
    hipMemsetAsync(Pbf,  0, (size_t)416*416*2, stream);

    // weight conversions (bf16, K zero-padded): all six in one launch
    auto cvtgrid = [](long long n){ return (unsigned)((n + 255) / 256); };
    cvt_pack_all_k<<<dim3(cvtgrid((long long)4600*1152), 6), 256, 0, stream>>>(
        Wih0, Wih0p, Whh0, Whh0p, Wih1, Wih1p, Whh1, Whh1p, Wih2, Wih2p, Whh2, Whh2p);
    cvt_catB2_k<<<dim3(500, 25), 256, 0, stream>>>(decW, odeW2, Bbf, BbfT);
    cvt_wx_k<<<cvtgrid((long long)400*NT_), 256, 0, stream>>>(odeW1, Wxbf);

    // activations + state init
    embed_bf_k<<<S_, 256, 0, stream>>>(tokens, emb, x0A);
    cvt_h0_k<<<(16*1150+255)/256, 256, 0, stream>>>(h0_0, h0b, 1150, 1152);
    cvt_h0_k<<<(16*1150+255)/256, 256, 0, stream>>>(h0_1, h1b, 1150, 1152);
    cvt_h0_k<<<(16*400+255)/256,  256, 0, stream>>>(h0_2, h2b, 400, 416);
    transpose16_k<<<(1150*16+255)/256, 256, 0, stream>>>(c0_0, c0b, 1150);
    transpose16_k<<<(1150*16+255)/256, 256, 0, stream>>>(c0_1, c1b, 1150);
    transpose16_k<<<(400*16+255)/256,  256, 0, stream>>>(c0_2, c2b, 400);

    // 3-layer LSTM, layer-pipelined wavefront, MFMA (per-step launches)
    for (int u = 0; u < S_ + 2; ++u)
        lstm_mfma_k<<<169, 1024, 0, stream>>>(u, x0A, ys0A, ys1A, x3,
            h0b, c0b, h1b, c1b, h2b, c2b,
            Wih0p, Whh0p, bih0, bhh0, Wih1p, Whh1p, bih1, bhh1, Wih2p, Whh2p, bih2, bhh2);

    // ODE factorization precompute: [Q|P] = Wx @ BbfT^T via MFMA, 16 K-slabs
    vecs_k<<<400, 256, 0, stream>>>(Wxbf, odeW1, decb, odeb2, dvec, bvec, wtd);
    gemm_odeT_k<<<dim3(7,4,16), 256, 0, stream>>>(Wxbf, BbfT, partials);
    reduce16bf_k<<<(320000+255)/256, 256, 0, stream>>>(partials, Qbf, Pbf);

    // Fused ODE: G0 + RK4(2 steps) + Abf (both halves) in one kernel
    ode_rk4_k<<<70, 512, 0, stream>>>(x3, Qbf, Pbf, dvec, bvec, wtd, odeb1, Abf);

    // MFMA decode (256x128 tiles) + fused log-softmax
    decode_mfma_k<<<dim3(250,5), 512, 0, stream>>>(Abf, Bbf, decb, odeb2, zout);
    softmax_k<<<SB_, 1024, 0, stream>>>(zout);
}